// Round 1
// baseline (5801.197 us; speedup 1.0000x reference)
//
#include <hip/hip_runtime.h>
#include <math.h>

#define Dk 1024
#define Ck 32
#define Nk 1024
#define Qk 1024
#define REGP 0.5f
#define NB 64
#define NT (Dk/NB)

// consts layout (floats)
#define CO_KAPPA 0
#define CO_NU    1
#define CO_NJ    2
#define CO_KN    34
#define CO_SCALE 66
#define CO_COMMON 98
#define CO_COEF  130
#define CO_BIASA 162
#define CO_LOGDET 194
#define CO_TOTAL 256

__device__ __forceinline__ void tri_decode(int lin, int& a, int& b) {
    int r = 0;
    while ((r + 1) * (r + 2) / 2 <= lin) ++r;
    a = r; b = lin - r * (r + 1) / 2;
}

__global__ void k_zero(float* p, int n) {
    int i = blockIdx.x * blockDim.x + threadIdx.x;
    if (i < n) p[i] = 0.f;
}

__global__ __launch_bounds__(256) void k_stats(const int* labels, const float* kappa,
                                               const float* nu, float* cons, int* cidx) {
    __shared__ int scnt[Ck];
    __shared__ float sk[2];
    int t = threadIdx.x;
    if (t < Ck) scnt[t] = 0;
    if (t == 0) {
        sk[0] = fabsf(kappa[0]) + 1e-6f;
        sk[1] = fmaxf(nu[0], (float)(Dk - 1) + 1e-6f);
        cons[CO_KAPPA] = sk[0];
        cons[CO_NU] = sk[1];
    }
    __syncthreads();
    for (int n = t; n < Nk; n += blockDim.x) {
        int l = labels[n];
        int pos = atomicAdd(&scnt[l], 1);
        cidx[l * Nk + pos] = n;
    }
    __syncthreads();
    if (t < Ck) {
        float kap = sk[0], nu_ = sk[1];
        float Njf = (float)scnt[t];
        float kN = kap + Njf;
        cons[CO_NJ + t] = Njf;
        cons[CO_KN + t] = kN;
        cons[CO_SCALE + t] = (kN + 1.0f) / ((nu_ + Njf - (float)Dk + 1.0f) * kN);
        float common = nu_ + Njf + 1.0f - (float)Dk;
        cons[CO_COMMON + t] = common;
        cons[CO_COEF + t] = 0.5f * (common + (float)Dk);
        cons[CO_BIASA + t] = lgammaf(0.5f * (common + (float)Dk)) - lgammaf(0.5f * common)
                             - 0.5f * (float)Dk * logf(common);
    }
}

__global__ __launch_bounds__(256) void k_mu(const float* sx, const float* m,
                                            const float* cons, const int* cidx, float* mu) {
    int c = blockIdx.x;
    int d = blockIdx.y * 256 + threadIdx.x;
    int Nj = (int)cons[CO_NJ + c];
    float kap = cons[CO_KAPPA], kN = cons[CO_KN + c];
    float acc = 0.f;
    for (int s = 0; s < Nj; ++s) acc += sx[(size_t)cidx[c * Nk + s] * Dk + d];
    mu[c * Dk + d] = (kap * m[d] + acc) / kN;
}

__device__ __forceinline__ float Lval(int r, int c_, const float* td, const float* tl) {
    if (c_ < r) return tl[(size_t)r * Dk + c_];
    if (c_ == r) return fabsf(td[r]);
    return 0.f;
}

// Sbase = L*L^T + kappa_ * m^T m  (full matrix, symmetric)
__global__ __launch_bounds__(256) void k_base(const float* td, const float* tl,
                                              const float* m, const float* cons, float* Sbase) {
    __shared__ float As[32][33], Bs[32][33];
    int ti = blockIdx.y, tj = blockIdx.x;
    int tx = threadIdx.x, ty = threadIdx.y; // 32 x 8
    int i0 = ti * 32, j0 = tj * 32;
    float acc[4] = {0.f, 0.f, 0.f, 0.f};
    int kend = min(i0, j0);
    for (int k0 = 0; k0 <= kend; k0 += 32) {
        for (int r = ty; r < 32; r += 8) {
            As[r][tx] = Lval(i0 + r, k0 + tx, td, tl);
            Bs[r][tx] = Lval(j0 + r, k0 + tx, td, tl);
        }
        __syncthreads();
        for (int kk = 0; kk < 32; ++kk) {
            float b = Bs[tx][kk];
#pragma unroll
            for (int r = 0; r < 4; ++r) acc[r] += As[ty + 8 * r][kk] * b;
        }
        __syncthreads();
    }
    float kap = cons[CO_KAPPA];
    float mj = m[j0 + tx];
#pragma unroll
    for (int r = 0; r < 4; ++r) {
        int i = i0 + ty + 8 * r;
        Sbase[(size_t)i * Dk + j0 + tx] = acc[r] + kap * m[i] * mj;
    }
}

// sigma_c = scale*(Sbase + Xc^T Xc - kN mu mu^T), lower-triangle tiles only (32x32 tiles)
__global__ __launch_bounds__(256) void k_sigma(const float* sx, const float* Sbase,
                                               const float* mu, const float* cons,
                                               const int* cidx, float* sig, int cbase) {
    int slot = blockIdx.x;
    int c = cbase + slot;
    int ti, tj;
    tri_decode(blockIdx.y, ti, tj);
    __shared__ float Xi[32][33], Xj[32][33];
    int tx = threadIdx.x, ty = threadIdx.y; // 32 x 8
    int i0 = ti * 32, j0 = tj * 32;
    int Nj = (int)cons[CO_NJ + c];
    float acc[4] = {0.f, 0.f, 0.f, 0.f};
    for (int s0 = 0; s0 < Nj; s0 += 32) {
        int ns = min(32, Nj - s0);
        for (int r = ty; r < 32; r += 8) {
            float vi = 0.f, vj = 0.f;
            if (r < ns) {
                int idx = cidx[c * Nk + s0 + r];
                vi = sx[(size_t)idx * Dk + i0 + tx];
                vj = sx[(size_t)idx * Dk + j0 + tx];
            }
            Xi[r][tx] = vi; Xj[r][tx] = vj;
        }
        __syncthreads();
        for (int s = 0; s < 32; ++s) {
            float xj = Xj[s][tx];
#pragma unroll
            for (int r = 0; r < 4; ++r) acc[r] += Xi[s][ty + 8 * r] * xj;
        }
        __syncthreads();
    }
    float scale = cons[CO_SCALE + c], kN = cons[CO_KN + c];
    float muj = mu[c * Dk + j0 + tx];
    float* A = sig + (size_t)slot * Dk * Dk;
#pragma unroll
    for (int r = 0; r < 4; ++r) {
        int i = i0 + ty + 8 * r;
        float v = Sbase[(size_t)i * Dk + j0 + tx] + acc[r] - kN * mu[c * Dk + i] * muj;
        A[(size_t)i * Dk + j0 + tx] = scale * v;
    }
}

// Cholesky panel: factor 64x64 diag block in LDS, then TRSM the rows below.
__global__ __launch_bounds__(256) void k_chol_panel(float* sig, float* cons, int p, int cbase) {
    int slot = blockIdx.x;
    float* A = sig + (size_t)slot * Dk * Dk;
    __shared__ float T[NB][NB + 1];
    __shared__ float di[NB];
    __shared__ float sdinv;
    int t = threadIdx.x;
    int b0 = p * NB;
    for (int idx = t; idx < NB * NB; idx += 256) {
        int r = idx >> 6, cc = idx & 63;
        T[r][cc] = A[(size_t)(b0 + r) * Dk + b0 + cc];
    }
    __syncthreads();
    float ldacc = 0.f;
    for (int j = 0; j < NB; ++j) {
        if (t == 0) {
            float dv = sqrtf(T[j][j]);
            T[j][j] = dv;
            sdinv = 1.f / dv;
            ldacc += 2.f * logf(dv);
        }
        __syncthreads();
        float dinv = sdinv;
        if (t > j && t < NB) T[t][j] *= dinv;
        __syncthreads();
        if (t > j && t < NB) {
            float lij = T[t][j];
            for (int k = j + 1; k <= t; ++k) T[t][k] -= lij * T[k][j];
        }
        __syncthreads();
    }
    if (t < NB) di[t] = 1.f / T[t][t];
    if (t == 0) atomicAdd(&cons[CO_LOGDET + cbase + slot], ldacc);
    __syncthreads();
    for (int idx = t; idx < NB * NB; idx += 256) {
        int r = idx >> 6, cc = idx & 63;
        A[(size_t)(b0 + r) * Dk + b0 + cc] = T[r][cc];
    }
    // TRSM: rows below the panel solve  x * T^T = a_row
#pragma unroll 1
    for (int i = b0 + NB + t; i < Dk; i += 256) {
        float* arow = A + (size_t)i * Dk + b0;
        float x[NB];
#pragma unroll
        for (int jj = 0; jj < NB; ++jj) {
            float s = arow[jj];
#pragma unroll
            for (int k = 0; k < jj; ++k) s -= x[k] * T[jj][k];
            x[jj] = s * di[jj];
        }
#pragma unroll
        for (int jj = 0; jj < NB; ++jj) arow[jj] = x[jj];
    }
}

// trailing update: A[I,J] -= Lpanel[I,:] * Lpanel[J,:]^T  (64x64 tiles, I>=J > p)
__global__ __launch_bounds__(256) void k_chol_trail(float* sig, int p) {
    int slot = blockIdx.y;
    float* A = sig + (size_t)slot * Dk * Dk;
    int a, b;
    tri_decode(blockIdx.x, a, b);
    int I = p + 1 + a, J = p + 1 + b;
    __shared__ float As[NB][NB + 1], Bs[NB][NB + 1];
    int t = threadIdx.x, tx = t & 15, ty = t >> 4;
    int pb = p * NB;
    for (int idx = t; idx < NB * NB; idx += 256) {
        int r = idx >> 6, k = idx & 63;
        As[r][k] = A[(size_t)(I * NB + r) * Dk + pb + k];
        Bs[r][k] = A[(size_t)(J * NB + r) * Dk + pb + k];
    }
    __syncthreads();
    float acc[4][4] = {};
    for (int kk = 0; kk < NB; ++kk) {
        float av[4], bv[4];
#pragma unroll
        for (int r = 0; r < 4; ++r) av[r] = As[ty * 4 + r][kk];
#pragma unroll
        for (int s = 0; s < 4; ++s) bv[s] = Bs[tx * 4 + s][kk];
#pragma unroll
        for (int r = 0; r < 4; ++r)
#pragma unroll
            for (int s = 0; s < 4; ++s) acc[r][s] += av[r] * bv[s];
    }
#pragma unroll
    for (int r = 0; r < 4; ++r)
#pragma unroll
        for (int s = 0; s < 4; ++s) {
            size_t off = (size_t)(I * NB + ty * 4 + r) * Dk + J * NB + tx * 4 + s;
            A[off] -= acc[r][s];
        }
}

// invert 64x64 diag block of L in place (writes zeros above diag)
__global__ __launch_bounds__(256) void k_trtri_diag(float* sig, int I) {
    int slot = blockIdx.x;
    float* A = sig + (size_t)slot * Dk * Dk;
    __shared__ float Lt[NB][NB + 1], Rt[NB][NB + 1];
    int t = threadIdx.x;
    int b0 = I * NB;
    for (int idx = t; idx < NB * NB; idx += 256) {
        int r = idx >> 6, cc = idx & 63;
        Lt[r][cc] = A[(size_t)(b0 + r) * Dk + b0 + cc];
        Rt[r][cc] = 0.f;
    }
    __syncthreads();
    if (t < NB) {
        int j = t;
        Rt[j][j] = 1.f / Lt[j][j];
        for (int i = j + 1; i < NB; ++i) {
            float s = 0.f;
            for (int k = j; k < i; ++k) s += Lt[i][k] * Rt[k][j];
            Rt[i][j] = -s / Lt[i][i];
        }
    }
    __syncthreads();
    for (int idx = t; idx < NB * NB; idx += 256) {
        int r = idx >> 6, cc = idx & 63;
        A[(size_t)(b0 + r) * Dk + b0 + cc] = Rt[r][cc];
    }
}

// step I, phase 1: T[I,J] = sum_{K=J..I-1} L[I,K] * R[K,J]; stash in (unused) upper block (J,I)
__global__ __launch_bounds__(256) void k_trtri_t(float* sig, int I) {
    int J = blockIdx.x, slot = blockIdx.y;
    float* A = sig + (size_t)slot * Dk * Dk;
    __shared__ float Sa[NB][NB + 1], Sb[NB][NB + 1];
    int t = threadIdx.x, tx = t & 15, ty = t >> 4;
    float acc[4][4] = {};
    for (int K = J; K < I; ++K) {
        for (int idx = t; idx < NB * NB; idx += 256) {
            int r = idx >> 6, k = idx & 63;
            Sa[r][k] = A[(size_t)(I * NB + r) * Dk + K * NB + k];  // L[I,K] original
            Sb[r][k] = A[(size_t)(K * NB + r) * Dk + J * NB + k];  // R[K,J] final
        }
        __syncthreads();
        for (int kk = 0; kk < NB; ++kk) {
            float av[4], bv[4];
#pragma unroll
            for (int r = 0; r < 4; ++r) av[r] = Sa[ty * 4 + r][kk];
#pragma unroll
            for (int s = 0; s < 4; ++s) bv[s] = Sb[kk][tx * 4 + s];
#pragma unroll
            for (int r = 0; r < 4; ++r)
#pragma unroll
                for (int s = 0; s < 4; ++s) acc[r][s] += av[r] * bv[s];
        }
        __syncthreads();
    }
#pragma unroll
    for (int r = 0; r < 4; ++r)
#pragma unroll
        for (int s = 0; s < 4; ++s)
            A[(size_t)(J * NB + ty * 4 + r) * Dk + I * NB + tx * 4 + s] = acc[r][s];
}

// step I, phase 2: R[I,J] = -R[I,I] * T[I,J]
__global__ __launch_bounds__(256) void k_trtri_scale(float* sig, int I) {
    int J = blockIdx.x, slot = blockIdx.y;
    float* A = sig + (size_t)slot * Dk * Dk;
    __shared__ float Ts[NB][NB + 1], Rs[NB][NB + 1];
    int t = threadIdx.x, tx = t & 15, ty = t >> 4;
    for (int idx = t; idx < NB * NB; idx += 256) {
        int r = idx >> 6, k = idx & 63;
        Ts[r][k] = A[(size_t)(J * NB + r) * Dk + I * NB + k];  // stashed T
        Rs[r][k] = A[(size_t)(I * NB + r) * Dk + I * NB + k];  // R[I,I]
    }
    __syncthreads();
    float acc[4][4] = {};
    for (int kk = 0; kk < NB; ++kk) {
        float av[4], bv[4];
#pragma unroll
        for (int r = 0; r < 4; ++r) av[r] = Rs[ty * 4 + r][kk];
#pragma unroll
        for (int s = 0; s < 4; ++s) bv[s] = Ts[kk][tx * 4 + s];
#pragma unroll
        for (int r = 0; r < 4; ++r)
#pragma unroll
            for (int s = 0; s < 4; ++s) acc[r][s] += av[r] * bv[s];
    }
#pragma unroll
    for (int r = 0; r < 4; ++r)
#pragma unroll
        for (int s = 0; s < 4; ++s)
            A[(size_t)(I * NB + ty * 4 + r) * Dk + J * NB + tx * 4 + s] = -acc[r][s];
}

// z = Rinv * (q - mu); accumulate sum(z^2) into zz[q,c]
__global__ __launch_bounds__(256) void k_zgemm(const float* sig, const float* qx,
                                               const float* mu, float* zz, int cbase) {
    int qt = blockIdx.x, it = blockIdx.y, slot = blockIdx.z;
    int c = cbase + slot;
    const float* R = sig + (size_t)slot * Dk * Dk;
    __shared__ float Rs[NB][NB + 1];
    __shared__ float Ds[NB][NB + 1];
    __shared__ float red[16][NB];
    int t = threadIdx.x, tx = t & 15, ty = t >> 4;
    float acc[4][4] = {};
    for (int kt = 0; kt <= it; ++kt) {
        for (int idx = t; idx < NB * NB; idx += 256) {
            int r = idx >> 6, k = idx & 63;
            Rs[r][k] = R[(size_t)(it * NB + r) * Dk + kt * NB + k];
        }
        for (int idx = t; idx < NB * NB; idx += 256) {
            int q_ = idx >> 6, k = idx & 63;
            Ds[k][q_] = qx[(size_t)(qt * NB + q_) * Dk + kt * NB + k] - mu[c * Dk + kt * NB + k];
        }
        __syncthreads();
        for (int kk = 0; kk < NB; ++kk) {
            float av[4], bv[4];
#pragma unroll
            for (int r = 0; r < 4; ++r) av[r] = Rs[ty * 4 + r][kk];
#pragma unroll
            for (int s = 0; s < 4; ++s) bv[s] = Ds[kk][tx * 4 + s];
#pragma unroll
            for (int r = 0; r < 4; ++r)
#pragma unroll
                for (int s = 0; s < 4; ++s) acc[r][s] += av[r] * bv[s];
        }
        __syncthreads();
    }
#pragma unroll
    for (int s = 0; s < 4; ++s) {
        float ps = 0.f;
#pragma unroll
        for (int r = 0; r < 4; ++r) ps += acc[r][s] * acc[r][s];
        red[ty][tx * 4 + s] = ps;
    }
    __syncthreads();
    if (t < NB) {
        float ssum = 0.f;
        for (int y = 0; y < 16; ++y) ssum += red[y][t];
        atomicAdd(&zz[(size_t)(qt * NB + t) * Ck + c], ssum);
    }
}

__global__ __launch_bounds__(64) void k_dd(const float* qx, const float* mu, float* dd) {
    int q = blockIdx.x, c = blockIdx.y, t = threadIdx.x;
    float s = 0.f;
    for (int d = t; d < Dk; d += 64) {
        float v = qx[(size_t)q * Dk + d] - mu[c * Dk + d];
        s += v * v;
    }
#pragma unroll
    for (int o = 32; o > 0; o >>= 1) s += __shfl_down(s, o, 64);
    if (t == 0) dd[(size_t)q * Ck + c] = s;
}

__global__ __launch_bounds__(256) void k_preds(const float* zz, const float* dd,
                                               const float* cons, float* out) {
    int idx = blockIdx.x * 256 + threadIdx.x;
    if (idx >= Qk * Ck) return;
    int c = idx & (Ck - 1);
    float common = cons[CO_COMMON + c];
    float dist = (1.f - REGP) * zz[idx] + REGP * dd[idx];
    float bias = cons[CO_BIASA + c] - 0.5f * cons[CO_LOGDET + c];
    out[idx] = bias - cons[CO_COEF + c] * log1pf(dist / common);
}

extern "C" void kernel_launch(void* const* d_in, const int* in_sizes, int n_in,
                              void* d_out, int out_size, void* d_ws, size_t ws_size,
                              hipStream_t stream) {
    const float* sx = (const float*)d_in[0];
    const float* qx = (const float*)d_in[1];
    const int* labels = (const int*)d_in[2];
    const float* m = (const float*)d_in[3];
    const float* kappa = (const float*)d_in[4];
    const float* nu = (const float*)d_in[5];
    const float* td = (const float*)d_in[6];
    const float* tl = (const float*)d_in[7];
    float* out = (float*)d_out;

    // class-group size chosen so workspace fits (sigma buffer = CG * D * D floats)
    int CG = Ck;
    while (CG > 1) {
        size_t need = ((size_t)Dk * Dk + (size_t)CG * Dk * Dk + (size_t)Ck * Dk
                       + 2 * (size_t)Qk * Ck + CO_TOTAL) * 4 + (size_t)Ck * Nk * 4;
        if (need <= ws_size) break;
        CG >>= 1;
    }

    float* Sbase = (float*)d_ws;
    float* sig = Sbase + (size_t)Dk * Dk;
    float* mu = sig + (size_t)CG * Dk * Dk;
    float* zz = mu + (size_t)Ck * Dk;
    float* dd = zz + (size_t)Qk * Ck;
    float* cons = dd + (size_t)Qk * Ck;
    int* cidx = (int*)(cons + CO_TOTAL);

    int nz = 2 * Qk * Ck + CO_TOTAL;
    k_zero<<<dim3((nz + 255) / 256), dim3(256), 0, stream>>>(zz, nz);
    k_stats<<<dim3(1), dim3(256), 0, stream>>>(labels, kappa, nu, cons, cidx);
    k_mu<<<dim3(Ck, Dk / 256), dim3(256), 0, stream>>>(sx, m, cons, cidx, mu);
    k_base<<<dim3(Dk / 32, Dk / 32), dim3(32, 8), 0, stream>>>(td, tl, m, cons, Sbase);

    for (int cbase = 0; cbase < Ck; cbase += CG) {
        k_sigma<<<dim3(CG, (32 * 33) / 2), dim3(32, 8), 0, stream>>>(sx, Sbase, mu, cons, cidx, sig, cbase);
        for (int p = 0; p < NT; ++p) {
            k_chol_panel<<<dim3(CG), dim3(256), 0, stream>>>(sig, cons, p, cbase);
            int n = NT - 1 - p;
            if (n > 0)
                k_chol_trail<<<dim3(n * (n + 1) / 2, CG), dim3(256), 0, stream>>>(sig, p);
        }
        for (int I = 0; I < NT; ++I) {
            k_trtri_diag<<<dim3(CG), dim3(256), 0, stream>>>(sig, I);
            if (I > 0) {
                k_trtri_t<<<dim3(I, CG), dim3(256), 0, stream>>>(sig, I);
                k_trtri_scale<<<dim3(I, CG), dim3(256), 0, stream>>>(sig, I);
            }
        }
        k_zgemm<<<dim3(Qk / NB, Dk / NB, CG), dim3(256), 0, stream>>>(sig, qx, mu, zz, cbase);
    }
    k_dd<<<dim3(Qk, Ck), dim3(64), 0, stream>>>(qx, mu, dd);
    k_preds<<<dim3((Qk * Ck + 255) / 256), dim3(256), 0, stream>>>(zz, dd, cons, out);
}

// Round 2
// 3746.378 us; speedup vs baseline: 1.5485x; 1.5485x over previous
//
#include <hip/hip_runtime.h>
#include <math.h>

#define Dk 1024
#define Ck 32
#define Nk 1024
#define Qk 1024
#define SHOTS 32
#define REGP 0.5f
#define NB 64
#define NT (Dk/NB)
#define NROWS (Qk + Nk + Ck)   // 2080 rows: queries, sorted support, mus

// consts layout (floats)
#define CO_KAPPA 0
#define CO_NU    1
#define CO_NJ    2
#define CO_KN    34
#define CO_SCALE 66
#define CO_COMMON 98
#define CO_COEF  130
#define CO_BIASA 162
#define CO_LOGDET 194   // scalar: logdet of shared B
#define CO_BIASF 200    // 32: final per-class bias (biasA - 0.5*logdet_sigma)
#define CO_TOTAL 256

__device__ __forceinline__ void tri_decode(int lin, int& a, int& b) {
    int r = 0;
    while ((r + 1) * (r + 2) / 2 <= lin) ++r;
    a = r; b = lin - r * (r + 1) / 2;
}

__global__ void k_zero(float* p, int n) {
    int i = blockIdx.x * blockDim.x + threadIdx.x;
    if (i < n) p[i] = 0.f;
}

__global__ __launch_bounds__(256) void k_stats(const int* labels, const float* kappa,
                                               const float* nu, float* cons, int* cidx) {
    __shared__ int scnt[Ck];
    __shared__ float sk[2];
    int t = threadIdx.x;
    if (t < Ck) scnt[t] = 0;
    if (t == 0) {
        sk[0] = fabsf(kappa[0]) + 1e-6f;
        sk[1] = fmaxf(nu[0], (float)(Dk - 1) + 1e-6f);
        cons[CO_KAPPA] = sk[0];
        cons[CO_NU] = sk[1];
    }
    __syncthreads();
    for (int n = t; n < Nk; n += blockDim.x) {
        int l = labels[n];
        int pos = atomicAdd(&scnt[l], 1);
        cidx[l * Nk + pos] = n;
    }
    __syncthreads();
    if (t < Ck) {
        float kap = sk[0], nu_ = sk[1];
        float Njf = (float)scnt[t];
        float kN = kap + Njf;
        cons[CO_NJ + t] = Njf;
        cons[CO_KN + t] = kN;
        cons[CO_SCALE + t] = (kN + 1.0f) / ((nu_ + Njf - (float)Dk + 1.0f) * kN);
        float common = nu_ + Njf + 1.0f - (float)Dk;
        cons[CO_COMMON + t] = common;
        cons[CO_COEF + t] = 0.5f * (common + (float)Dk);
        cons[CO_BIASA + t] = lgammaf(0.5f * (common + (float)Dk)) - lgammaf(0.5f * common)
                             - 0.5f * (float)Dk * logf(common);
    }
}

__global__ __launch_bounds__(256) void k_mu(const float* sx, const float* m,
                                            const float* cons, const int* cidx, float* mu) {
    int c = blockIdx.x;
    int d = blockIdx.y * 256 + threadIdx.x;
    int Nj = (int)cons[CO_NJ + c];
    float kap = cons[CO_KAPPA], kN = cons[CO_KN + c];
    float acc = 0.f;
    for (int s = 0; s < Nj; ++s) acc += sx[(size_t)cidx[c * Nk + s] * Dk + d];
    mu[c * Dk + d] = (kap * m[d] + acc) / kN;
}

__device__ __forceinline__ float Lval(int r, int c_, const float* td, const float* tl) {
    if (c_ < r) return tl[(size_t)r * Dk + c_];
    if (c_ == r) return fabsf(td[r]);
    return 0.f;
}

// B = L*L^T + kappa_ * m^T m  (full symmetric matrix)
__global__ __launch_bounds__(256) void k_base(const float* td, const float* tl,
                                              const float* m, const float* cons, float* Bm) {
    __shared__ float As[32][33], Bs[32][33];
    int ti = blockIdx.y, tj = blockIdx.x;
    int tx = threadIdx.x, ty = threadIdx.y; // 32 x 8
    int i0 = ti * 32, j0 = tj * 32;
    float acc[4] = {0.f, 0.f, 0.f, 0.f};
    int kend = min(i0, j0);
    for (int k0 = 0; k0 <= kend; k0 += 32) {
        for (int r = ty; r < 32; r += 8) {
            As[r][tx] = Lval(i0 + r, k0 + tx, td, tl);
            Bs[r][tx] = Lval(j0 + r, k0 + tx, td, tl);
        }
        __syncthreads();
        for (int kk = 0; kk < 32; ++kk) {
            float b = Bs[tx][kk];
#pragma unroll
            for (int r = 0; r < 4; ++r) acc[r] += As[ty + 8 * r][kk] * b;
        }
        __syncthreads();
    }
    float kap = cons[CO_KAPPA];
    float mj = m[j0 + tx];
#pragma unroll
    for (int r = 0; r < 4; ++r) {
        int i = i0 + ty + 8 * r;
        Bm[(size_t)i * Dk + j0 + tx] = acc[r] + kap * m[i] * mj;
    }
}

// Cholesky panel on the single shared B. Accumulates logdet(B) into cons.
__global__ __launch_bounds__(256) void k_chol_panel(float* A, float* cons, int p) {
    __shared__ float T[NB][NB + 1];
    __shared__ float di[NB];
    __shared__ float sdinv;
    int t = threadIdx.x;
    int b0 = p * NB;
    for (int idx = t; idx < NB * NB; idx += 256) {
        int r = idx >> 6, cc = idx & 63;
        T[r][cc] = A[(size_t)(b0 + r) * Dk + b0 + cc];
    }
    __syncthreads();
    float ldacc = 0.f;
    for (int j = 0; j < NB; ++j) {
        if (t == 0) {
            float dv = sqrtf(T[j][j]);
            T[j][j] = dv;
            sdinv = 1.f / dv;
            ldacc += 2.f * logf(dv);
        }
        __syncthreads();
        float dinv = sdinv;
        if (t > j && t < NB) T[t][j] *= dinv;
        __syncthreads();
        if (t > j && t < NB) {
            float lij = T[t][j];
            for (int k = j + 1; k <= t; ++k) T[t][k] -= lij * T[k][j];
        }
        __syncthreads();
    }
    if (t < NB) di[t] = 1.f / T[t][t];
    if (t == 0) atomicAdd(&cons[CO_LOGDET], ldacc);
    __syncthreads();
    for (int idx = t; idx < NB * NB; idx += 256) {
        int r = idx >> 6, cc = idx & 63;
        A[(size_t)(b0 + r) * Dk + b0 + cc] = T[r][cc];
    }
    // TRSM rows below the panel: x * T^T = a_row
#pragma unroll 1
    for (int i = b0 + NB + t; i < Dk; i += 256) {
        float* arow = A + (size_t)i * Dk + b0;
        float x[NB];
#pragma unroll
        for (int jj = 0; jj < NB; ++jj) {
            float s = arow[jj];
#pragma unroll
            for (int k = 0; k < jj; ++k) s -= x[k] * T[jj][k];
            x[jj] = s * di[jj];
        }
#pragma unroll
        for (int jj = 0; jj < NB; ++jj) arow[jj] = x[jj];
    }
}

// trailing update: A[I,J] -= Lp[I,:] * Lp[J,:]^T  (64x64 tiles, I>=J > p)
__global__ __launch_bounds__(256) void k_chol_trail(float* A, int p) {
    int a, b;
    tri_decode(blockIdx.x, a, b);
    int I = p + 1 + a, J = p + 1 + b;
    __shared__ float As[NB][NB + 1], Bs[NB][NB + 1];
    int t = threadIdx.x, tx = t & 15, ty = t >> 4;
    int pb = p * NB;
    for (int idx = t; idx < NB * NB; idx += 256) {
        int r = idx >> 6, k = idx & 63;
        As[r][k] = A[(size_t)(I * NB + r) * Dk + pb + k];
        Bs[r][k] = A[(size_t)(J * NB + r) * Dk + pb + k];
    }
    __syncthreads();
    float acc[4][4] = {};
    for (int kk = 0; kk < NB; ++kk) {
        float av[4], bv[4];
#pragma unroll
        for (int r = 0; r < 4; ++r) av[r] = As[ty * 4 + r][kk];
#pragma unroll
        for (int s = 0; s < 4; ++s) bv[s] = Bs[tx * 4 + s][kk];
#pragma unroll
        for (int r = 0; r < 4; ++r)
#pragma unroll
            for (int s = 0; s < 4; ++s) acc[r][s] += av[r] * bv[s];
    }
#pragma unroll
    for (int r = 0; r < 4; ++r)
#pragma unroll
        for (int s = 0; s < 4; ++s) {
            size_t off = (size_t)(I * NB + ty * 4 + r) * Dk + J * NB + tx * 4 + s;
            A[off] -= acc[r][s];
        }
}

// Dinv[I] = inv(L_II), 64x64 lower-triangular, one block per panel
__global__ __launch_bounds__(256) void k_dinv(const float* L, float* Dinv) {
    int I = blockIdx.x;
    __shared__ float Lt[NB][NB + 1], Rt[NB][NB + 1];
    int t = threadIdx.x;
    int b0 = I * NB;
    for (int idx = t; idx < NB * NB; idx += 256) {
        int r = idx >> 6, cc = idx & 63;
        Lt[r][cc] = L[(size_t)(b0 + r) * Dk + b0 + cc];
        Rt[r][cc] = 0.f;
    }
    __syncthreads();
    if (t < NB) {
        int j = t;
        Rt[j][j] = 1.f / Lt[j][j];
        for (int i = j + 1; i < NB; ++i) {
            float s = 0.f;
            for (int k = j; k < i; ++k) s += Lt[i][k] * Rt[k][j];
            Rt[i][j] = -s / Lt[i][i];
        }
    }
    __syncthreads();
    for (int idx = t; idx < NB * NB; idx += 256) {
        int r = idx >> 6, cc = idx & 63;
        Dinv[I * NB * NB + r * NB + cc] = Rt[r][cc];
    }
}

// Gather all rows to transform: [queries; class-sorted support; mus]
__global__ void k_buildA(const float* qx, const float* sx, const float* mu,
                         const int* cidx, float* Y) {
    int r = blockIdx.y;
    int d = blockIdx.x * 256 + threadIdx.x;
    const float* src;
    if (r < Qk) src = qx + (size_t)r * Dk;
    else if (r < Qk + Nk) {
        int n = r - Qk;
        int c = n >> 5, s = n & 31;
        src = sx + (size_t)cidx[c * Nk + s] * Dk;
    } else src = mu + (size_t)(r - Qk - Nk) * Dk;
    Y[(size_t)r * Dk + d] = src[d];
}

// Forward-subst step ip: Y[:,ip] = (A[:,ip] - sum_{k<ip} Y[:,k] L[ip,k]^T) * Dinv[ip]^T
__global__ __launch_bounds__(256) void k_solve(const float* L, const float* Dinv,
                                               float* Y, int ip) {
    int rt = blockIdx.x;
    int r0 = rt * NB;
    __shared__ float Sa[NB][NB + 1], Sb[NB][NB + 1];
    int t = threadIdx.x, tx = t & 15, ty = t >> 4;
    float acc[4][4] = {};
    for (int k = 0; k < ip; ++k) {
        for (int idx = t; idx < NB * NB; idx += 256) {
            int r = idx >> 6, cc = idx & 63;
            int gr = r0 + r;
            Sa[r][cc] = (gr < NROWS) ? Y[(size_t)gr * Dk + k * NB + cc] : 0.f;
            Sb[r][cc] = L[(size_t)(ip * NB + r) * Dk + k * NB + cc];
        }
        __syncthreads();
        for (int kk = 0; kk < NB; ++kk) {
            float av[4], bv[4];
#pragma unroll
            for (int r = 0; r < 4; ++r) av[r] = Sa[ty * 4 + r][kk];
#pragma unroll
            for (int s = 0; s < 4; ++s) bv[s] = Sb[tx * 4 + s][kk];
#pragma unroll
            for (int r = 0; r < 4; ++r)
#pragma unroll
                for (int s = 0; s < 4; ++s) acc[r][s] += av[r] * bv[s];
        }
        __syncthreads();
    }
    // R = A - acc  (into Sa)
#pragma unroll
    for (int rr = 0; rr < 4; ++rr)
#pragma unroll
        for (int cc = 0; cc < 4; ++cc) {
            int gr = r0 + ty * 4 + rr;
            float a = (gr < NROWS) ? Y[(size_t)gr * Dk + ip * NB + tx * 4 + cc] : 0.f;
            Sa[ty * 4 + rr][tx * 4 + cc] = a - acc[rr][cc];
        }
    // Sb = Dinv[ip], lower-masked
    for (int idx = t; idx < NB * NB; idx += 256) {
        int a_ = idx >> 6, b_ = idx & 63;
        Sb[a_][b_] = (b_ <= a_) ? Dinv[ip * NB * NB + a_ * NB + b_] : 0.f;
    }
    __syncthreads();
    float out4[4][4] = {};
    for (int kk = 0; kk < NB; ++kk) {
        float av[4], bv[4];
#pragma unroll
        for (int r = 0; r < 4; ++r) av[r] = Sa[ty * 4 + r][kk];
#pragma unroll
        for (int s = 0; s < 4; ++s) bv[s] = Sb[tx * 4 + s][kk];
#pragma unroll
        for (int r = 0; r < 4; ++r)
#pragma unroll
            for (int s = 0; s < 4; ++s) out4[r][s] += av[r] * bv[s];
    }
#pragma unroll
    for (int rr = 0; rr < 4; ++rr)
#pragma unroll
        for (int ss = 0; ss < 4; ++ss) {
            int gr = r0 + ty * 4 + rr;
            if (gr < NROWS)
                Y[(size_t)gr * Dk + ip * NB + tx * 4 + ss] = out4[rr][ss];
        }
}

// P[n][q] = Ysup_row(n) . Yq_row(q), n in [0,1056) = [support(1024); mu(32)]
__global__ __launch_bounds__(256) void k_P(const float* Y, float* P) {
    int qt = blockIdx.x, nt = blockIdx.y;
    __shared__ float As[NB][NB + 1], Bs[NB][NB + 1];
    int t = threadIdx.x, tx = t & 15, ty = t >> 4;
    float acc[4][4] = {};
    for (int kt = 0; kt < NT; ++kt) {
        for (int idx = t; idx < NB * NB; idx += 256) {
            int r = idx >> 6, k = idx & 63;
            int n = nt * NB + r;
            As[r][k] = (n < Nk + Ck) ? Y[(size_t)(Qk + n) * Dk + kt * NB + k] : 0.f;
            Bs[r][k] = Y[(size_t)(qt * NB + r) * Dk + kt * NB + k];
        }
        __syncthreads();
        for (int kk = 0; kk < NB; ++kk) {
            float av[4], bv[4];
#pragma unroll
            for (int r = 0; r < 4; ++r) av[r] = As[ty * 4 + r][kk];
#pragma unroll
            for (int s = 0; s < 4; ++s) bv[s] = Bs[tx * 4 + s][kk];
#pragma unroll
            for (int r = 0; r < 4; ++r)
#pragma unroll
                for (int s = 0; s < 4; ++s) acc[r][s] += av[r] * bv[s];
        }
        __syncthreads();
    }
#pragma unroll
    for (int r = 0; r < 4; ++r)
#pragma unroll
        for (int s = 0; s < 4; ++s)
            P[(size_t)(nt * NB + ty * 4 + r) * Qk + qt * NB + tx * 4 + s] = acc[r][s];
}

// per-class 33x33 Gram -> M_c = S^{-1} + V^T V; also munorm
__global__ __launch_bounds__(256) void k_gram(const float* Y, const float* cons,
                                              float* Mbuf, float* munorm) {
    int c = blockIdx.x, t = threadIdx.x;
    __shared__ float Yc[33][NB + 1];
    int iu[5], ju[5];
#pragma unroll
    for (int u = 0; u < 5; ++u) {
        int e = t + u * 256;
        iu[u] = e / 33; ju[u] = e % 33;
    }
    float acc[5] = {};
    for (int d0 = 0; d0 < Dk; d0 += NB) {
        for (int e = t; e < 33 * NB; e += 256) {
            int i = e >> 6, k = e & 63;
            int row = (i < 32) ? (Qk + c * 32 + i) : (Qk + Nk + c);
            Yc[i][k] = Y[(size_t)row * Dk + d0 + k];
        }
        __syncthreads();
#pragma unroll
        for (int u = 0; u < 5; ++u) {
            int e = t + u * 256;
            if (e < 1089) {
                float s = 0.f;
                for (int k = 0; k < NB; ++k) s += Yc[iu[u]][k] * Yc[ju[u]][k];
                acc[u] += s;
            }
        }
        __syncthreads();
    }
    float kN = cons[CO_KN + c];
#pragma unroll
    for (int u = 0; u < 5; ++u) {
        int e = t + u * 256;
        if (e < 1089) {
            int i = iu[u], j = ju[u];
            float v = acc[u];
            if (i == j) v += (i < 32) ? 1.f : (-1.f / kN);
            Mbuf[c * 33 * 34 + i * 34 + j] = v;
            if (e == 1088) munorm[c] = acc[u];
        }
    }
}

// per-class: LDL^T of M (33x33), log|det M|, explicit inverse, final bias
__global__ __launch_bounds__(64) void k_minv(const float* Mbuf, float* cons, float* Minv) {
    int c = blockIdx.x, t = threadIdx.x;
    __shared__ float Ml[33][34];
    __shared__ float Dv[33];
    __shared__ float Z[33][34];
    for (int e = t; e < 33 * 34; e += 64) Ml[e / 34][e % 34] = Mbuf[c * 33 * 34 + e];
    __syncthreads();
    for (int j = 0; j < 33; ++j) {
        if (t == 0) {
            float s = Ml[j][j];
            for (int k = 0; k < j; ++k) s -= Ml[j][k] * Ml[j][k] * Dv[k];
            Dv[j] = s;
        }
        __syncthreads();
        if (t > j && t < 33) {
            float s = Ml[t][j];
            for (int k = 0; k < j; ++k) s -= Ml[t][k] * Ml[j][k] * Dv[k];
            Ml[t][j] = s / Dv[j];
        }
        __syncthreads();
    }
    if (t < 33) {
        // forward: L z = e_t (unit lower)
        for (int i = 0; i < 33; ++i) {
            float s = (i == t) ? 1.f : 0.f;
            for (int k = 0; k < i; ++k) s -= Ml[i][k] * Z[k][t];
            Z[i][t] = s;
        }
        // diag + backward: x_i = z_i/D_i - sum_{k>i} L[k][i] x_k (in place)
        for (int i = 32; i >= 0; --i) {
            float s = Z[i][t] / Dv[i];
            for (int k = i + 1; k < 33; ++k) s -= Ml[k][i] * Z[k][t];
            Z[i][t] = s;
        }
    }
    __syncthreads();
    for (int e = t; e < 33 * 34; e += 64) Minv[c * 33 * 34 + e] = Z[e / 34][e % 34];
    if (t == 0) {
        float ld = 0.f;
        for (int j = 0; j < 33; ++j) ld += logf(fabsf(Dv[j]));
        float scale = cons[CO_SCALE + c], kN = cons[CO_KN + c];
        float logdet = (float)Dk * logf(scale) + cons[CO_LOGDET] + logf(kN) + ld;
        cons[CO_BIASF + c] = cons[CO_BIASA + c] - 0.5f * logdet;
    }
}

__global__ __launch_bounds__(64) void k_qnorm(const float* Y, float* qnorm) {
    int q = blockIdx.x, t = threadIdx.x;
    float s = 0.f;
    for (int d = t; d < Dk; d += 64) {
        float v = Y[(size_t)q * Dk + d];
        s += v * v;
    }
#pragma unroll
    for (int o = 32; o > 0; o >>= 1) s += __shfl_down(s, o, 64);
    if (t == 0) qnorm[q] = s;
}

// original-space ||q - mu||^2
__global__ __launch_bounds__(64) void k_dd(const float* qx, const float* mu, float* dd) {
    int q = blockIdx.x, c = blockIdx.y, t = threadIdx.x;
    float s = 0.f;
    for (int d = t; d < Dk; d += 64) {
        float v = qx[(size_t)q * Dk + d] - mu[c * Dk + d];
        s += v * v;
    }
#pragma unroll
    for (int o = 32; o > 0; o >>= 1) s += __shfl_down(s, o, 64);
    if (t == 0) dd[(size_t)q * Ck + c] = s;
}

// final: per (q-tile, class): w, quad form, dist, preds
__global__ __launch_bounds__(64) void k_final(const float* P, const float* Minv,
                                              const float* Mbuf, const float* munorm,
                                              const float* qnorm, const float* dd,
                                              const float* cons, float* out) {
    int qt = blockIdx.x, c = blockIdx.y, t = threadIdx.x;
    __shared__ float Mi[33][34];
    __shared__ float wL[33][65];
    __shared__ float gsm[33];
    for (int e = t; e < 33 * 34; e += 64) Mi[e / 34][e % 34] = Minv[c * 33 * 34 + e];
    if (t < 33) gsm[t] = (t < 32) ? Mbuf[c * 33 * 34 + t * 34 + 32] : munorm[c];
    __syncthreads();
    for (int e = t; e < 33 * 64; e += 64) {
        int i = e >> 6, qq = e & 63;
        int prow = (i < 32) ? (c * 32 + i) : (Nk + c);
        wL[i][qq] = P[(size_t)prow * Qk + qt * 64 + qq] - gsm[i];
    }
    __syncthreads();
    float quad = 0.f;
#pragma unroll 1
    for (int i = 0; i < 33; ++i) {
        float v = 0.f;
        for (int j = 0; j < 33; ++j) v += Mi[i][j] * wL[j][t];
        quad += v * wL[i][t];
    }
    float w32 = wL[32][t];
    float mn = munorm[c];
    int q = qt * 64 + t;
    float e2 = qnorm[q] - 2.f * w32 - mn;
    float scale = cons[CO_SCALE + c], common = cons[CO_COMMON + c];
    float dist = (1.f - REGP) / scale * (e2 - quad) + REGP * dd[(size_t)q * Ck + c];
    out[(size_t)q * Ck + c] = cons[CO_BIASF + c] - cons[CO_COEF + c] * log1pf(dist / common);
}

extern "C" void kernel_launch(void* const* d_in, const int* in_sizes, int n_in,
                              void* d_out, int out_size, void* d_ws, size_t ws_size,
                              hipStream_t stream) {
    const float* sx = (const float*)d_in[0];
    const float* qx = (const float*)d_in[1];
    const int* labels = (const int*)d_in[2];
    const float* m = (const float*)d_in[3];
    const float* kappa = (const float*)d_in[4];
    const float* nu = (const float*)d_in[5];
    const float* td = (const float*)d_in[6];
    const float* tl = (const float*)d_in[7];
    float* out = (float*)d_out;

    float* Bm = (float*)d_ws;                       // D*D
    float* Dinv = Bm + (size_t)Dk * Dk;             // 16*64*64
    float* Yall = Dinv + NT * NB * NB;              // 2112*D (padded rows)
    float* P = Yall + (size_t)2112 * Dk;            // 1088*Qk (padded rows)
    float* mu = P + (size_t)1088 * Qk;              // Ck*D
    float* Mbuf = mu + Ck * Dk;                     // Ck*33*34
    float* Minv = Mbuf + Ck * 33 * 34;              // Ck*33*34
    float* qnorm = Minv + Ck * 33 * 34;             // Qk
    float* munorm = qnorm + Qk;                     // Ck
    float* dd = munorm + Ck;                        // Qk*Ck
    float* cons = dd + Qk * Ck;                     // CO_TOTAL
    int* cidx = (int*)(cons + CO_TOTAL);            // Ck*Nk ints

    k_zero<<<dim3(1), dim3(256), 0, stream>>>(cons, CO_TOTAL);
    k_stats<<<dim3(1), dim3(256), 0, stream>>>(labels, kappa, nu, cons, cidx);
    k_mu<<<dim3(Ck, Dk / 256), dim3(256), 0, stream>>>(sx, m, cons, cidx, mu);
    k_base<<<dim3(Dk / 32, Dk / 32), dim3(32, 8), 0, stream>>>(td, tl, m, cons, Bm);

    for (int p = 0; p < NT; ++p) {
        k_chol_panel<<<dim3(1), dim3(256), 0, stream>>>(Bm, cons, p);
        int n = NT - 1 - p;
        if (n > 0)
            k_chol_trail<<<dim3(n * (n + 1) / 2), dim3(256), 0, stream>>>(Bm, p);
    }
    k_dinv<<<dim3(NT), dim3(256), 0, stream>>>(Bm, Dinv);

    k_buildA<<<dim3(Dk / 256, NROWS), dim3(256), 0, stream>>>(qx, sx, mu, cidx, Yall);
    for (int ip = 0; ip < NT; ++ip)
        k_solve<<<dim3((NROWS + NB - 1) / NB), dim3(256), 0, stream>>>(Bm, Dinv, Yall, ip);

    k_gram<<<dim3(Ck), dim3(256), 0, stream>>>(Yall, cons, Mbuf, munorm);
    k_minv<<<dim3(Ck), dim3(64), 0, stream>>>(Mbuf, cons, Minv);
    k_qnorm<<<dim3(Qk), dim3(64), 0, stream>>>(Yall, qnorm);
    k_P<<<dim3(Qk / NB, (Nk + Ck + NB - 1) / NB), dim3(256), 0, stream>>>(Yall, P);
    k_dd<<<dim3(Qk, Ck), dim3(64), 0, stream>>>(qx, mu, dd);
    k_final<<<dim3(Qk / NB, Ck), dim3(64), 0, stream>>>(P, Minv, Mbuf, munorm, qnorm, dd, cons, out);
}

// Round 3
// 3379.372 us; speedup vs baseline: 1.7166x; 1.1086x over previous
//
#include <hip/hip_runtime.h>
#include <math.h>

#define Dk 1024
#define Ck 32
#define Nk 1024
#define Qk 1024
#define SHOTS 32
#define REGP 0.5f
#define NB 64
#define NT (Dk/NB)
#define NROWS (Qk + Nk + Ck)   // 2080 rows: queries, sorted support, mus

// consts layout (floats)
#define CO_KAPPA 0
#define CO_NU    1
#define CO_NJ    2
#define CO_KN    34
#define CO_SCALE 66
#define CO_COMMON 98
#define CO_COEF  130
#define CO_BIASA 162
#define CO_LOGDET 194   // scalar: logdet of shared B
#define CO_BIASF 200    // 32: final per-class bias
#define CO_TOTAL 256

__device__ __forceinline__ void tri_decode(int lin, int& a, int& b) {
    int r = 0;
    while ((r + 1) * (r + 2) / 2 <= lin) ++r;
    a = r; b = lin - r * (r + 1) / 2;
}

__global__ void k_zero(float* p, int n) {
    int i = blockIdx.x * blockDim.x + threadIdx.x;
    if (i < n) p[i] = 0.f;
}

__global__ __launch_bounds__(256) void k_stats(const int* labels, const float* kappa,
                                               const float* nu, float* cons, int* cidx) {
    __shared__ int scnt[Ck];
    __shared__ float sk[2];
    int t = threadIdx.x;
    if (t < Ck) scnt[t] = 0;
    if (t == 0) {
        sk[0] = fabsf(kappa[0]) + 1e-6f;
        sk[1] = fmaxf(nu[0], (float)(Dk - 1) + 1e-6f);
        cons[CO_KAPPA] = sk[0];
        cons[CO_NU] = sk[1];
    }
    __syncthreads();
    for (int n = t; n < Nk; n += blockDim.x) {
        int l = labels[n];
        int pos = atomicAdd(&scnt[l], 1);
        cidx[l * Nk + pos] = n;
    }
    __syncthreads();
    if (t < Ck) {
        float kap = sk[0], nu_ = sk[1];
        float Njf = (float)scnt[t];
        float kN = kap + Njf;
        cons[CO_NJ + t] = Njf;
        cons[CO_KN + t] = kN;
        cons[CO_SCALE + t] = (kN + 1.0f) / ((nu_ + Njf - (float)Dk + 1.0f) * kN);
        float common = nu_ + Njf + 1.0f - (float)Dk;
        cons[CO_COMMON + t] = common;
        cons[CO_COEF + t] = 0.5f * (common + (float)Dk);
        cons[CO_BIASA + t] = lgammaf(0.5f * (common + (float)Dk)) - lgammaf(0.5f * common)
                             - 0.5f * (float)Dk * logf(common);
    }
}

__global__ __launch_bounds__(256) void k_mu(const float* sx, const float* m,
                                            const float* cons, const int* cidx, float* mu) {
    int c = blockIdx.x;
    int d = blockIdx.y * 256 + threadIdx.x;
    int Nj = (int)cons[CO_NJ + c];
    float kap = cons[CO_KAPPA], kN = cons[CO_KN + c];
    float acc = 0.f;
    for (int s = 0; s < Nj; ++s) acc += sx[(size_t)cidx[c * Nk + s] * Dk + d];
    mu[c * Dk + d] = (kap * m[d] + acc) / kN;
}

__device__ __forceinline__ float Lval(int r, int c_, const float* td, const float* tl) {
    if (c_ < r) return tl[(size_t)r * Dk + c_];
    if (c_ == r) return fabsf(td[r]);
    return 0.f;
}

// B = L*L^T + kappa_ * m^T m  (full symmetric matrix)
__global__ __launch_bounds__(256) void k_base(const float* td, const float* tl,
                                              const float* m, const float* cons, float* Bm) {
    __shared__ float As[32][33], Bs[32][33];
    int ti = blockIdx.y, tj = blockIdx.x;
    int tx = threadIdx.x, ty = threadIdx.y; // 32 x 8
    int i0 = ti * 32, j0 = tj * 32;
    float acc[4] = {0.f, 0.f, 0.f, 0.f};
    int kend = min(i0, j0);
    for (int k0 = 0; k0 <= kend; k0 += 32) {
        for (int r = ty; r < 32; r += 8) {
            As[r][tx] = Lval(i0 + r, k0 + tx, td, tl);
            Bs[r][tx] = Lval(j0 + r, k0 + tx, td, tl);
        }
        __syncthreads();
        for (int kk = 0; kk < 32; ++kk) {
            float b = Bs[tx][kk];
#pragma unroll
            for (int r = 0; r < 4; ++r) acc[r] += As[ty + 8 * r][kk] * b;
        }
        __syncthreads();
    }
    float kap = cons[CO_KAPPA];
    float mj = m[j0 + tx];
#pragma unroll
    for (int r = 0; r < 4; ++r) {
        int i = i0 + ty + 8 * r;
        Bm[(size_t)i * Dk + j0 + tx] = acc[r] + kap * m[i] * mj;
    }
}

// Factor 64x64 diag block (parallel rank-1 updates), logdet, and invert it.
// Upper triangle of the stored diag block ends up garbage — never read downstream.
__global__ __launch_bounds__(256) void k_chol_diag(float* A, float* cons, float* Dinv, int p) {
    __shared__ float T[NB][NB + 1];
    __shared__ float Rt[NB][NB + 1];
    __shared__ float sdinv;
    int t = threadIdx.x;
    int b0 = p * NB;
    for (int idx = t; idx < NB * NB; idx += 256) {
        int r = idx >> 6, cc = idx & 63;
        T[r][cc] = A[(size_t)(b0 + r) * Dk + b0 + cc];
    }
    __syncthreads();
    for (int j = 0; j < NB; ++j) {
        if (t == 0) {
            float dv = sqrtf(T[j][j]);
            T[j][j] = dv;
            sdinv = 1.f / dv;
        }
        __syncthreads();
        if (t > j && t < NB) T[t][j] *= sdinv;
        __syncthreads();
        // rank-1 update of trailing square, fully parallel (skip cols <= j)
        int W = NB - 1 - j;
        for (int e = t; e < W * NB; e += 256) {
            int r = j + 1 + (e >> 6), c = e & 63;
            if (c > j) T[r][c] -= T[r][j] * T[c][j];
        }
        __syncthreads();
    }
    if (t == 0) {
        float ld = 0.f;
        for (int j = 0; j < NB; ++j) ld += 2.f * logf(T[j][j]);
        atomicAdd(&cons[CO_LOGDET], ld);
    }
    // write back factored block
    for (int idx = t; idx < NB * NB; idx += 256) {
        int r = idx >> 6, cc = idx & 63;
        A[(size_t)(b0 + r) * Dk + b0 + cc] = T[r][cc];
    }
    // invert: column j per thread (forward substitution)
    if (t < NB) {
        int j = t;
        Rt[j][j] = 1.f / T[j][j];
        for (int i = j + 1; i < NB; ++i) {
            float s = 0.f;
            for (int k = j; k < i; ++k) s += T[i][k] * Rt[k][j];
            Rt[i][j] = -s / T[i][i];
        }
    }
    __syncthreads();
    for (int idx = t; idx < NB * NB; idx += 256) {
        int r = idx >> 6, cc = idx & 63;
        Dinv[p * NB * NB + r * NB + cc] = (cc <= r) ? Rt[r][cc] : 0.f;
    }
}

// TRSM as GEMM: L[I,p] = A[I,p] * Dinv_p^T, one 64x64 tile per block
__global__ __launch_bounds__(256) void k_trsm(float* A, const float* Dinv, int p) {
    int I = p + 1 + blockIdx.x;
    __shared__ float As[NB][NB + 1], Ds[NB][NB + 1];
    int t = threadIdx.x, tx = t & 15, ty = t >> 4;
    for (int idx = t; idx < NB * NB; idx += 256) {
        int r = idx >> 6, k = idx & 63;
        As[r][k] = A[(size_t)(I * NB + r) * Dk + p * NB + k];
        Ds[r][k] = Dinv[p * NB * NB + r * NB + k];
    }
    __syncthreads();
    float acc[4][4] = {};
    for (int kk = 0; kk < NB; ++kk) {
        float av[4], bv[4];
#pragma unroll
        for (int r = 0; r < 4; ++r) av[r] = As[ty * 4 + r][kk];
#pragma unroll
        for (int s = 0; s < 4; ++s) bv[s] = Ds[tx * 4 + s][kk];
#pragma unroll
        for (int r = 0; r < 4; ++r)
#pragma unroll
            for (int s = 0; s < 4; ++s) acc[r][s] += av[r] * bv[s];
    }
#pragma unroll
    for (int r = 0; r < 4; ++r)
#pragma unroll
        for (int s = 0; s < 4; ++s)
            A[(size_t)(I * NB + ty * 4 + r) * Dk + p * NB + tx * 4 + s] = acc[r][s];
}

// trailing update: A[I,J] -= Lp[I,:] * Lp[J,:]^T  (64x64 tiles, I>=J > p)
__global__ __launch_bounds__(256) void k_chol_trail(float* A, int p) {
    int a, b;
    tri_decode(blockIdx.x, a, b);
    int I = p + 1 + a, J = p + 1 + b;
    __shared__ float As[NB][NB + 1], Bs[NB][NB + 1];
    int t = threadIdx.x, tx = t & 15, ty = t >> 4;
    int pb = p * NB;
    for (int idx = t; idx < NB * NB; idx += 256) {
        int r = idx >> 6, k = idx & 63;
        As[r][k] = A[(size_t)(I * NB + r) * Dk + pb + k];
        Bs[r][k] = A[(size_t)(J * NB + r) * Dk + pb + k];
    }
    __syncthreads();
    float acc[4][4] = {};
    for (int kk = 0; kk < NB; ++kk) {
        float av[4], bv[4];
#pragma unroll
        for (int r = 0; r < 4; ++r) av[r] = As[ty * 4 + r][kk];
#pragma unroll
        for (int s = 0; s < 4; ++s) bv[s] = Bs[tx * 4 + s][kk];
#pragma unroll
        for (int r = 0; r < 4; ++r)
#pragma unroll
            for (int s = 0; s < 4; ++s) acc[r][s] += av[r] * bv[s];
    }
#pragma unroll
    for (int r = 0; r < 4; ++r)
#pragma unroll
        for (int s = 0; s < 4; ++s) {
            size_t off = (size_t)(I * NB + ty * 4 + r) * Dk + J * NB + tx * 4 + s;
            A[off] -= acc[r][s];
        }
}

// Gather all rows to transform: [queries; class-sorted support; mus]
__global__ void k_buildA(const float* qx, const float* sx, const float* mu,
                         const int* cidx, float* Y) {
    int r = blockIdx.y;
    int d = blockIdx.x * 256 + threadIdx.x;
    const float* src;
    if (r < Qk) src = qx + (size_t)r * Dk;
    else if (r < Qk + Nk) {
        int n = r - Qk;
        int c = n >> 5, s = n & 31;
        src = sx + (size_t)cidx[c * Nk + s] * Dk;
    } else src = mu + (size_t)(r - Qk - Nk) * Dk;
    Y[(size_t)r * Dk + d] = src[d];
}

// Forward-subst step ip: Y[:,ip] = (A[:,ip] - sum_{k<ip} Y[:,k] L[ip,k]^T) * Dinv[ip]^T
__global__ __launch_bounds__(256) void k_solve(const float* L, const float* Dinv,
                                               float* Y, int ip) {
    int rt = blockIdx.x;
    int r0 = rt * NB;
    __shared__ float Sa[NB][NB + 1], Sb[NB][NB + 1];
    int t = threadIdx.x, tx = t & 15, ty = t >> 4;
    float acc[4][4] = {};
    for (int k = 0; k < ip; ++k) {
        for (int idx = t; idx < NB * NB; idx += 256) {
            int r = idx >> 6, cc = idx & 63;
            int gr = r0 + r;
            Sa[r][cc] = (gr < NROWS) ? Y[(size_t)gr * Dk + k * NB + cc] : 0.f;
            Sb[r][cc] = L[(size_t)(ip * NB + r) * Dk + k * NB + cc];
        }
        __syncthreads();
        for (int kk = 0; kk < NB; ++kk) {
            float av[4], bv[4];
#pragma unroll
            for (int r = 0; r < 4; ++r) av[r] = Sa[ty * 4 + r][kk];
#pragma unroll
            for (int s = 0; s < 4; ++s) bv[s] = Sb[tx * 4 + s][kk];
#pragma unroll
            for (int r = 0; r < 4; ++r)
#pragma unroll
                for (int s = 0; s < 4; ++s) acc[r][s] += av[r] * bv[s];
        }
        __syncthreads();
    }
    // R = A - acc  (into Sa)
#pragma unroll
    for (int rr = 0; rr < 4; ++rr)
#pragma unroll
        for (int cc = 0; cc < 4; ++cc) {
            int gr = r0 + ty * 4 + rr;
            float a = (gr < NROWS) ? Y[(size_t)gr * Dk + ip * NB + tx * 4 + cc] : 0.f;
            Sa[ty * 4 + rr][tx * 4 + cc] = a - acc[rr][cc];
        }
    // Sb = Dinv[ip] (stored lower-masked)
    for (int idx = t; idx < NB * NB; idx += 256) {
        int a_ = idx >> 6, b_ = idx & 63;
        Sb[a_][b_] = Dinv[ip * NB * NB + a_ * NB + b_];
    }
    __syncthreads();
    float out4[4][4] = {};
    for (int kk = 0; kk < NB; ++kk) {
        float av[4], bv[4];
#pragma unroll
        for (int r = 0; r < 4; ++r) av[r] = Sa[ty * 4 + r][kk];
#pragma unroll
        for (int s = 0; s < 4; ++s) bv[s] = Sb[tx * 4 + s][kk];
#pragma unroll
        for (int r = 0; r < 4; ++r)
#pragma unroll
            for (int s = 0; s < 4; ++s) out4[r][s] += av[r] * bv[s];
    }
#pragma unroll
    for (int rr = 0; rr < 4; ++rr)
#pragma unroll
        for (int ss = 0; ss < 4; ++ss) {
            int gr = r0 + ty * 4 + rr;
            if (gr < NROWS)
                Y[(size_t)gr * Dk + ip * NB + tx * 4 + ss] = out4[rr][ss];
        }
}

// P[n][q] = Ysup_row(n) . Yq_row(q), n in [0,1056) = [support(1024); mu(32)]
__global__ __launch_bounds__(256) void k_P(const float* Y, float* P) {
    int qt = blockIdx.x, nt = blockIdx.y;
    __shared__ float As[NB][NB + 1], Bs[NB][NB + 1];
    int t = threadIdx.x, tx = t & 15, ty = t >> 4;
    float acc[4][4] = {};
    for (int kt = 0; kt < NT; ++kt) {
        for (int idx = t; idx < NB * NB; idx += 256) {
            int r = idx >> 6, k = idx & 63;
            int n = nt * NB + r;
            As[r][k] = (n < Nk + Ck) ? Y[(size_t)(Qk + n) * Dk + kt * NB + k] : 0.f;
            Bs[r][k] = Y[(size_t)(qt * NB + r) * Dk + kt * NB + k];
        }
        __syncthreads();
        for (int kk = 0; kk < NB; ++kk) {
            float av[4], bv[4];
#pragma unroll
            for (int r = 0; r < 4; ++r) av[r] = As[ty * 4 + r][kk];
#pragma unroll
            for (int s = 0; s < 4; ++s) bv[s] = Bs[tx * 4 + s][kk];
#pragma unroll
            for (int r = 0; r < 4; ++r)
#pragma unroll
                for (int s = 0; s < 4; ++s) acc[r][s] += av[r] * bv[s];
        }
        __syncthreads();
    }
#pragma unroll
    for (int r = 0; r < 4; ++r)
#pragma unroll
        for (int s = 0; s < 4; ++s)
            P[(size_t)(nt * NB + ty * 4 + r) * Qk + qt * NB + tx * 4 + s] = acc[r][s];
}

// per-class 33x33 Gram -> M_c = S^{-1} + V^T V; also munorm
__global__ __launch_bounds__(256) void k_gram(const float* Y, const float* cons,
                                              float* Mbuf, float* munorm) {
    int c = blockIdx.x, t = threadIdx.x;
    __shared__ float Yc[33][NB + 1];
    int iu[5], ju[5];
#pragma unroll
    for (int u = 0; u < 5; ++u) {
        int e = t + u * 256;
        iu[u] = e / 33; ju[u] = e % 33;
    }
    float acc[5] = {};
    for (int d0 = 0; d0 < Dk; d0 += NB) {
        for (int e = t; e < 33 * NB; e += 256) {
            int i = e >> 6, k = e & 63;
            int row = (i < 32) ? (Qk + c * 32 + i) : (Qk + Nk + c);
            Yc[i][k] = Y[(size_t)row * Dk + d0 + k];
        }
        __syncthreads();
#pragma unroll
        for (int u = 0; u < 5; ++u) {
            int e = t + u * 256;
            if (e < 1089) {
                float s = 0.f;
                for (int k = 0; k < NB; ++k) s += Yc[iu[u]][k] * Yc[ju[u]][k];
                acc[u] += s;
            }
        }
        __syncthreads();
    }
    float kN = cons[CO_KN + c];
#pragma unroll
    for (int u = 0; u < 5; ++u) {
        int e = t + u * 256;
        if (e < 1089) {
            int i = iu[u], j = ju[u];
            float v = acc[u];
            if (i == j) v += (i < 32) ? 1.f : (-1.f / kN);
            Mbuf[c * 33 * 34 + i * 34 + j] = v;
            if (e == 1088) munorm[c] = acc[u];
        }
    }
}

// per-class: LDL^T of M (33x33), log|det M|, explicit inverse, final bias
__global__ __launch_bounds__(64) void k_minv(const float* Mbuf, float* cons, float* Minv) {
    int c = blockIdx.x, t = threadIdx.x;
    __shared__ float Ml[33][34];
    __shared__ float Dv[33];
    __shared__ float Z[33][34];
    for (int e = t; e < 33 * 34; e += 64) Ml[e / 34][e % 34] = Mbuf[c * 33 * 34 + e];
    __syncthreads();
    for (int j = 0; j < 33; ++j) {
        if (t == 0) {
            float s = Ml[j][j];
            for (int k = 0; k < j; ++k) s -= Ml[j][k] * Ml[j][k] * Dv[k];
            Dv[j] = s;
        }
        __syncthreads();
        if (t > j && t < 33) {
            float s = Ml[t][j];
            for (int k = 0; k < j; ++k) s -= Ml[t][k] * Ml[j][k] * Dv[k];
            Ml[t][j] = s / Dv[j];
        }
        __syncthreads();
    }
    if (t < 33) {
        for (int i = 0; i < 33; ++i) {
            float s = (i == t) ? 1.f : 0.f;
            for (int k = 0; k < i; ++k) s -= Ml[i][k] * Z[k][t];
            Z[i][t] = s;
        }
        for (int i = 32; i >= 0; --i) {
            float s = Z[i][t] / Dv[i];
            for (int k = i + 1; k < 33; ++k) s -= Ml[k][i] * Z[k][t];
            Z[i][t] = s;
        }
    }
    __syncthreads();
    for (int e = t; e < 33 * 34; e += 64) Minv[c * 33 * 34 + e] = Z[e / 34][e % 34];
    if (t == 0) {
        float ld = 0.f;
        for (int j = 0; j < 33; ++j) ld += logf(fabsf(Dv[j]));
        float scale = cons[CO_SCALE + c], kN = cons[CO_KN + c];
        float logdet = (float)Dk * logf(scale) + cons[CO_LOGDET] + logf(kN) + ld;
        cons[CO_BIASF + c] = cons[CO_BIASA + c] - 0.5f * logdet;
    }
}

__global__ __launch_bounds__(64) void k_qnorm(const float* Y, float* qnorm) {
    int q = blockIdx.x, t = threadIdx.x;
    float s = 0.f;
    for (int d = t; d < Dk; d += 64) {
        float v = Y[(size_t)q * Dk + d];
        s += v * v;
    }
#pragma unroll
    for (int o = 32; o > 0; o >>= 1) s += __shfl_down(s, o, 64);
    if (t == 0) qnorm[q] = s;
}

// original-space ||q - mu||^2
__global__ __launch_bounds__(64) void k_dd(const float* qx, const float* mu, float* dd) {
    int q = blockIdx.x, c = blockIdx.y, t = threadIdx.x;
    float s = 0.f;
    for (int d = t; d < Dk; d += 64) {
        float v = qx[(size_t)q * Dk + d] - mu[c * Dk + d];
        s += v * v;
    }
#pragma unroll
    for (int o = 32; o > 0; o >>= 1) s += __shfl_down(s, o, 64);
    if (t == 0) dd[(size_t)q * Ck + c] = s;
}

// final: per (q-tile, class): w, quad form, dist, preds
__global__ __launch_bounds__(64) void k_final(const float* P, const float* Minv,
                                              const float* Mbuf, const float* munorm,
                                              const float* qnorm, const float* dd,
                                              const float* cons, float* out) {
    int qt = blockIdx.x, c = blockIdx.y, t = threadIdx.x;
    __shared__ float Mi[33][34];
    __shared__ float wL[33][65];
    __shared__ float gsm[33];
    for (int e = t; e < 33 * 34; e += 64) Mi[e / 34][e % 34] = Minv[c * 33 * 34 + e];
    if (t < 33) gsm[t] = (t < 32) ? Mbuf[c * 33 * 34 + t * 34 + 32] : munorm[c];
    __syncthreads();
    for (int e = t; e < 33 * 64; e += 64) {
        int i = e >> 6, qq = e & 63;
        int prow = (i < 32) ? (c * 32 + i) : (Nk + c);
        wL[i][qq] = P[(size_t)prow * Qk + qt * 64 + qq] - gsm[i];
    }
    __syncthreads();
    float quad = 0.f;
#pragma unroll 1
    for (int i = 0; i < 33; ++i) {
        float v = 0.f;
        for (int j = 0; j < 33; ++j) v += Mi[i][j] * wL[j][t];
        quad += v * wL[i][t];
    }
    float w32 = wL[32][t];
    float mn = munorm[c];
    int q = qt * 64 + t;
    float e2 = qnorm[q] - 2.f * w32 - mn;
    float scale = cons[CO_SCALE + c], common = cons[CO_COMMON + c];
    float dist = (1.f - REGP) / scale * (e2 - quad) + REGP * dd[(size_t)q * Ck + c];
    out[(size_t)q * Ck + c] = cons[CO_BIASF + c] - cons[CO_COEF + c] * log1pf(dist / common);
}

extern "C" void kernel_launch(void* const* d_in, const int* in_sizes, int n_in,
                              void* d_out, int out_size, void* d_ws, size_t ws_size,
                              hipStream_t stream) {
    const float* sx = (const float*)d_in[0];
    const float* qx = (const float*)d_in[1];
    const int* labels = (const int*)d_in[2];
    const float* m = (const float*)d_in[3];
    const float* kappa = (const float*)d_in[4];
    const float* nu = (const float*)d_in[5];
    const float* td = (const float*)d_in[6];
    const float* tl = (const float*)d_in[7];
    float* out = (float*)d_out;

    float* Bm = (float*)d_ws;                       // D*D
    float* Dinv = Bm + (size_t)Dk * Dk;             // 16*64*64
    float* Yall = Dinv + NT * NB * NB;              // 2112*D (padded rows)
    float* P = Yall + (size_t)2112 * Dk;            // 1088*Qk (padded rows)
    float* mu = P + (size_t)1088 * Qk;              // Ck*D
    float* Mbuf = mu + Ck * Dk;                     // Ck*33*34
    float* Minv = Mbuf + Ck * 33 * 34;              // Ck*33*34
    float* qnorm = Minv + Ck * 33 * 34;             // Qk
    float* munorm = qnorm + Qk;                     // Ck
    float* dd = munorm + Ck;                        // Qk*Ck
    float* cons = dd + Qk * Ck;                     // CO_TOTAL
    int* cidx = (int*)(cons + CO_TOTAL);            // Ck*Nk ints

    k_zero<<<dim3(1), dim3(256), 0, stream>>>(cons, CO_TOTAL);
    k_stats<<<dim3(1), dim3(256), 0, stream>>>(labels, kappa, nu, cons, cidx);
    k_mu<<<dim3(Ck, Dk / 256), dim3(256), 0, stream>>>(sx, m, cons, cidx, mu);
    k_base<<<dim3(Dk / 32, Dk / 32), dim3(32, 8), 0, stream>>>(td, tl, m, cons, Bm);

    for (int p = 0; p < NT; ++p) {
        k_chol_diag<<<dim3(1), dim3(256), 0, stream>>>(Bm, cons, Dinv, p);
        int n = NT - 1 - p;
        if (n > 0) {
            k_trsm<<<dim3(n), dim3(256), 0, stream>>>(Bm, Dinv, p);
            k_chol_trail<<<dim3(n * (n + 1) / 2), dim3(256), 0, stream>>>(Bm, p);
        }
    }

    k_buildA<<<dim3(Dk / 256, NROWS), dim3(256), 0, stream>>>(qx, sx, mu, cidx, Yall);
    for (int ip = 0; ip < NT; ++ip)
        k_solve<<<dim3((NROWS + NB - 1) / NB), dim3(256), 0, stream>>>(Bm, Dinv, Yall, ip);

    k_gram<<<dim3(Ck), dim3(256), 0, stream>>>(Yall, cons, Mbuf, munorm);
    k_minv<<<dim3(Ck), dim3(64), 0, stream>>>(Mbuf, cons, Minv);
    k_qnorm<<<dim3(Qk), dim3(64), 0, stream>>>(Yall, qnorm);
    k_P<<<dim3(Qk / NB, (Nk + Ck + NB - 1) / NB), dim3(256), 0, stream>>>(Yall, P);
    k_dd<<<dim3(Qk, Ck), dim3(64), 0, stream>>>(qx, mu, dd);
    k_final<<<dim3(Qk / NB, Ck), dim3(64), 0, stream>>>(P, Minv, Mbuf, munorm, qnorm, dd, cons, out);
}

// Round 4
// 1933.095 us; speedup vs baseline: 3.0010x; 1.7482x over previous
//
#include <hip/hip_runtime.h>
#include <hip/hip_cooperative_groups.h>
#include <math.h>

namespace cg = cooperative_groups;

#define Dk 1024
#define Ck 32
#define Nk 1024
#define Qk 1024
#define REGP 0.5f
#define NB 64
#define NT (Dk/NB)
#define NROWSV (Qk + Nk + Ck + 1)   // 2081 rows: queries, sorted support, mus, m
#define NRT 33                      // ceil(2081/64)

// consts layout (floats)
#define CO_KAPPA 0
#define CO_NU    1
#define CO_NJ    2
#define CO_KN    34
#define CO_SCALE 66
#define CO_COMMON 98
#define CO_COEF  130
#define CO_BIASA 162
#define CO_BIASF 200
#define CO_TOTAL 256

// workspace offsets (floats)
#define OFF_Y    0u
#define OFF_P    2162688u            // 2112*1024
#define OFF_DINV 3276800u            // + 1088*1024
#define OFF_MU   3342336u            // + 16*4096
#define OFF_QM   3375104u            // + 32*1024
#define OFF_MB   3407872u            // + 32*1024
#define OFF_MI   3447040u            // + 32*1224
#define OFF_QNY  3486208u            // + 32*1224
#define OFF_QNO  3487232u
#define OFF_MUN  3488256u
#define OFF_GMM  3488288u
#define OFF_EX   3488320u
#define OFF_CONS 3488336u
#define OFF_CIDX 3488592u            // ints

__device__ __forceinline__ float wave_red(float s) {
#pragma unroll
    for (int o = 32; o > 0; o >>= 1) s += __shfl_down(s, o, 64);
    return s;
}

// load 64x64 tile transposed into LDS: dst[k*68 + r] = src[(rowbase+r)*ld + colbase + k]
__device__ __forceinline__ void ld_tileT(float* dst, const float* src, int ld,
                                         int rowbase, int rowmax, int colbase, int t) {
    for (int idx = t; idx < NB * NB; idx += 256) {
        int r = idx >> 6, k = idx & 63;
        int gr = rowbase + r;
        dst[k * 68 + r] = (gr < rowmax) ? src[(size_t)gr * ld + colbase + k] : 0.f;
    }
}

// C[r][c] += sum_k A[r][k]*B[c][k] with At[k*68+r], Bt[k*68+c]; 16x16 threads, 4x4 acc
__device__ __forceinline__ void gemm16(const float* At, const float* Bt,
                                       float acc[4][4], int tx, int ty) {
#pragma unroll 4
    for (int kk = 0; kk < NB; ++kk) {
        float4 a = *(const float4*)(At + kk * 68 + ty * 4);
        float4 b = *(const float4*)(Bt + kk * 68 + tx * 4);
        float av[4] = {a.x, a.y, a.z, a.w};
        float bv[4] = {b.x, b.y, b.z, b.w};
#pragma unroll
        for (int r = 0; r < 4; ++r)
#pragma unroll
            for (int s = 0; s < 4; ++s) acc[r][s] += av[r] * bv[s];
    }
}

__global__ __launch_bounds__(256) void k_all(const float* sx, const float* qx,
                                             const int* labels, const float* mvec,
                                             const float* kappa, const float* nu,
                                             const float* td, const float* tl,
                                             float* W, float* out) {
    cg::grid_group grid = cg::this_grid();
    __shared__ __align__(16) float smem[9216];
    float* smA = smem;            // 4352 floats
    float* smB = smem + 4352;     // 4352 floats
    float* sX  = smem + 8704;     // 512 floats

    float* Y     = W + OFF_Y;
    float* P     = W + OFF_P;
    float* Dinv  = W + OFF_DINV;
    float* mu    = W + OFF_MU;
    float* QM    = W + OFF_QM;
    float* Mbuf  = W + OFF_MB;
    float* Minv  = W + OFF_MI;
    float* qny   = W + OFF_QNY;
    float* qno   = W + OFF_QNO;
    float* mun2o = W + OFF_MUN;
    float* gmm   = W + OFF_GMM;
    float* extraf= W + OFF_EX;
    float* cons  = W + OFF_CONS;
    int*   cidx  = (int*)(W + OFF_CIDX);

    const int b = blockIdx.x;
    const int t = threadIdx.x;
    const int tx = t & 15, ty = t >> 4;
    const int lane = t & 63, wv = t >> 6;

    // ---------------- P0: stats, ldA0, Dinv16, qn_orig, qx/m copies ----------------
    if (b == 0) {
        int* scnt = (int*)sX;
        if (t < Ck) scnt[t] = 0;
        __syncthreads();
        for (int n = t; n < Nk; n += 256) {
            int l = labels[n];
            int pos = atomicAdd(&scnt[l], 1);
            cidx[l * Nk + pos] = n;
        }
        __syncthreads();
        if (t < Ck) {
            float kap = fabsf(kappa[0]) + 1e-6f;
            float nu_ = fmaxf(nu[0], (float)(Dk - 1) + 1e-6f);
            float Njf = (float)scnt[t];
            float kN = kap + Njf;
            if (t == 0) { cons[CO_KAPPA] = kap; cons[CO_NU] = nu_; }
            cons[CO_NJ + t] = Njf;
            cons[CO_KN + t] = kN;
            cons[CO_SCALE + t] = (kN + 1.0f) / ((nu_ + Njf - (float)Dk + 1.0f) * kN);
            float common = nu_ + Njf + 1.0f - (float)Dk;
            cons[CO_COMMON + t] = common;
            cons[CO_COEF + t] = 0.5f * (common + (float)Dk);
            cons[CO_BIASA + t] = lgammaf(0.5f * (common + (float)Dk)) - lgammaf(0.5f * common)
                                 - 0.5f * (float)Dk * logf(common);
        }
    } else if (b == 1) {
        float s = 0.f;
        for (int i = t; i < Dk; i += 256) s += logf(fabsf(td[i]));
        s = wave_red(s);
        if (lane == 0) sX[wv] = s;
        __syncthreads();
        if (t == 0) extraf[0] = 2.f * (sX[0] + sX[1] + sX[2] + sX[3]);
    } else if (b >= 2 && b < 18) {
        // invert diag block I of Lhat (lower-tri, diag=|td|)
        int I = b - 2, b0 = I * NB;
        for (int idx = t; idx < NB * NB; idx += 256) {
            int r = idx >> 6, c = idx & 63;
            float v;
            if (c < r) v = tl[(size_t)(b0 + r) * Dk + b0 + c];
            else if (c == r) v = fabsf(td[b0 + r]);
            else v = 0.f;
            smA[r * 68 + c] = v;
        }
        __syncthreads();
        if (t < NB) {
            int j = t;
            smB[j * 68 + j] = 1.f / smA[j * 68 + j];
            for (int i = j + 1; i < NB; ++i) {
                float s = 0.f;
                for (int k = j; k < i; ++k) s += smA[i * 68 + k] * smB[k * 68 + j];
                smB[i * 68 + j] = -s / smA[i * 68 + i];
            }
        }
        __syncthreads();
        for (int idx = t; idx < NB * NB; idx += 256) {
            int r = idx >> 6, c = idx & 63;
            Dinv[I * NB * NB + r * NB + c] = (c <= r) ? smB[r * 68 + c] : 0.f;
        }
    } else if (b >= 32 && b < 96) {
        int rbase = (b - 32) * 16;
        for (int j = wv; j < 16; j += 4) {
            const float* row = qx + (size_t)(rbase + j) * Dk;
            float s = 0.f;
            for (int d = lane; d < Dk; d += 64) { float v = row[d]; s += v * v; }
            s = wave_red(s);
            if (lane == 0) qno[rbase + j] = s;
        }
    } else if (b >= 96 && b < 160) {
        int rbase = (b - 96) * 16;
        for (int j = 0; j < 16; ++j) {
            int r = rbase + j;
            ((float4*)(Y + (size_t)r * Dk))[t] = ((const float4*)(qx + (size_t)r * Dk))[t];
        }
    } else if (b == 160) {
        ((float4*)(Y + (size_t)(Qk + Nk + Ck) * Dk))[t] = ((const float4*)mvec)[t];
    }
    grid.sync();

    // ---------------- P1: mu, sorted-support copy ----------------
    if (b < 128) {
        int c = b >> 2;
        int d = ((b & 3) << 8) + t;
        int Nj = (int)cons[CO_NJ + c];
        float kap = cons[CO_KAPPA], kN = cons[CO_KN + c];
        float acc = 0.f;
        for (int s = 0; s < Nj; ++s) acc += sx[(size_t)cidx[c * Nk + s] * Dk + d];
        mu[c * Dk + d] = (kap * mvec[d] + acc) / kN;
    } else if (b < 192) {
        int rbase = (b - 128) * 16;
        for (int j = 0; j < 16; ++j) {
            int n = rbase + j;
            int srcrow = cidx[(n >> 5) * Nk + (n & 31)];
            ((float4*)(Y + (size_t)(Qk + n) * Dk))[t] = ((const float4*)(sx + (size_t)srcrow * Dk))[t];
        }
    }
    grid.sync();

    // ---------------- P2: mu rows into Y, mu norms, QM gemm ----------------
    if (b == 0) {
        for (int c = 0; c < Ck; ++c)
            ((float4*)(Y + (size_t)(Qk + Nk + c) * Dk))[t] = ((const float4*)(mu + (size_t)c * Dk))[t];
    } else if (b >= 32 && b < 64) {
        int c = b - 32;
        if (wv == 0) {
            float s = 0.f;
            for (int d = lane; d < Dk; d += 64) { float v = mu[c * Dk + d]; s += v * v; }
            s = wave_red(s);
            if (lane == 0) mun2o[c] = s;
        }
    } else if (b >= 64 && b < 80) {
        int qt = b - 64;
        float acc[4][4] = {};
        for (int kt = 0; kt < NT; ++kt) {
            ld_tileT(smA, mu, Dk, 0, Ck, kt * NB, t);
            ld_tileT(smB, qx, Dk, qt * NB, Qk, kt * NB, t);
            __syncthreads();
            gemm16(smA, smB, acc, tx, ty);
            __syncthreads();
        }
#pragma unroll
        for (int r = 0; r < 4; ++r) {
            int c = ty * 4 + r;
            if (c < Ck)
#pragma unroll
                for (int s = 0; s < 4; ++s)
                    QM[(size_t)c * Qk + qt * NB + tx * 4 + s] = acc[r][s];
        }
    }
    grid.sync();

    // ---------------- P3: right-looking triangular solve Y = A * Lhat^-T ----------------
    for (int ip = 0; ip < NT; ++ip) {
        if (b < NRT) {
            int rt = b;
            float acc[4][4] = {};
            ld_tileT(smA, Y, Dk, rt * NB, NROWSV, ip * NB, t);
            ld_tileT(smB, Dinv + ip * NB * NB, NB, 0, NB, 0, t);
            __syncthreads();
            gemm16(smA, smB, acc, tx, ty);
            __syncthreads();
#pragma unroll
            for (int r = 0; r < 4; ++r) {
                int gr = rt * NB + ty * 4 + r;
                if (gr < NROWSV)
#pragma unroll
                    for (int s = 0; s < 4; ++s)
                        Y[(size_t)gr * Dk + ip * NB + tx * 4 + s] = acc[r][s];
            }
        }
        grid.sync();
        int ntask = NRT * (NT - 1 - ip);
        for (int tau = b; tau < ntask; tau += 256) {
            int rt = tau % NRT;
            int kt2 = ip + 1 + tau / NRT;
            float acc[4][4] = {};
            ld_tileT(smA, Y, Dk, rt * NB, NROWSV, ip * NB, t);
            ld_tileT(smB, tl, Dk, kt2 * NB, Dk, ip * NB, t);
            __syncthreads();
            gemm16(smA, smB, acc, tx, ty);
            __syncthreads();
#pragma unroll
            for (int r = 0; r < 4; ++r) {
                int gr = rt * NB + ty * 4 + r;
                if (gr < NROWSV)
#pragma unroll
                    for (int s = 0; s < 4; ++s)
                        Y[(size_t)gr * Dk + kt2 * NB + tx * 4 + s] -= acc[r][s];
            }
        }
        grid.sync();
    }

    // ---------------- P4: P gemm (272), gram (32), qn_y (64) ----------------
    for (int tau = b; tau < 368; tau += 256) {
        if (tau < 272) {
            int qt = tau & 15, nt = tau >> 4;
            float acc[4][4] = {};
            for (int kt = 0; kt < NT; ++kt) {
                if (nt < 16) {
                    ld_tileT(smA, Y + (size_t)Qk * Dk, Dk, nt * NB, Nk, kt * NB, t);
                } else {
                    for (int idx = t; idx < NB * NB; idx += 256) {
                        int r = idx >> 6, k = idx & 63;
                        float v = 0.f;
                        if (r < 32) v = Y[(size_t)(Qk + Nk + r) * Dk + kt * NB + k];
                        else if (r == 32) v = Y[(size_t)(Qk + Nk + Ck) * Dk + kt * NB + k];
                        smA[k * 68 + r] = v;
                    }
                }
                ld_tileT(smB, Y, Dk, qt * NB, Qk, kt * NB, t);
                __syncthreads();
                gemm16(smA, smB, acc, tx, ty);
                __syncthreads();
            }
#pragma unroll
            for (int r = 0; r < 4; ++r) {
                int n = nt * NB + ty * 4 + r;
                if (n < Nk + Ck + 1)
#pragma unroll
                    for (int s = 0; s < 4; ++s)
                        P[(size_t)n * Qk + qt * NB + tx * 4 + s] = acc[r][s];
            }
        } else if (tau < 304) {
            int c = tau - 272;
            float accg[5];
            int iu[5], ju[5];
#pragma unroll
            for (int u = 0; u < 5; ++u) {
                int e = t + u * 256;
                iu[u] = e / 34; ju[u] = e - iu[u] * 34;
                accg[u] = 0.f;
            }
            for (int kt = 0; kt < NT; ++kt) {
                for (int e2 = t; e2 < 34 * NB; e2 += 256) {
                    int i = e2 >> 6, k = e2 & 63;
                    int yr = (i < 32) ? (Qk + c * 32 + i) : ((i == 32) ? (Qk + Nk + c) : (Qk + Nk + Ck));
                    smA[i * 68 + k] = Y[(size_t)yr * Dk + kt * NB + k];
                }
                __syncthreads();
#pragma unroll
                for (int u = 0; u < 5; ++u) {
                    int e = t + u * 256;
                    if (e < 1156) {
                        float s = 0.f;
                        for (int k = 0; k < NB; ++k) s += smA[iu[u] * 68 + k] * smA[ju[u] * 68 + k];
                        accg[u] += s;
                    }
                }
                __syncthreads();
            }
            float kN = cons[CO_KN + c], kap = cons[CO_KAPPA];
#pragma unroll
            for (int u = 0; u < 5; ++u) {
                int e = t + u * 256;
                if (e < 1156) {
                    int i = iu[u], j = ju[u];
                    float v = accg[u];
                    if (i == 32 && j == 32) { gmm[c] = v; v += -1.f / kN; }
                    else if (i == 33 && j == 33) v += 1.f / kap;
                    else if (i == j) v += 1.f;
                    Mbuf[c * 1224 + i * 36 + j] = v;
                }
            }
        } else {
            int rbase = (tau - 304) * 16;
            for (int j = wv; j < 16; j += 4) {
                const float* row = Y + (size_t)(rbase + j) * Dk;
                float s = 0.f;
                for (int d = lane; d < Dk; d += 64) { float v = row[d]; s += v * v; }
                s = wave_red(s);
                if (lane == 0) qny[rbase + j] = s;
            }
        }
    }
    grid.sync();

    // ---------------- P5: 34x34 LDL + inverse + bias per class ----------------
    if (b < Ck) {
        int c = b;
        float* Ml = smA;   // stride 35
        float* Z  = smB;   // stride 35
        float* Dv = sX;
        for (int e = t; e < 34 * 34; e += 256) {
            int i = e / 34, j = e - i * 34;
            Ml[i * 35 + j] = Mbuf[c * 1224 + i * 36 + j];
        }
        __syncthreads();
        for (int j = 0; j < 34; ++j) {
            if (t == 0) {
                float s = Ml[j * 35 + j];
                for (int k = 0; k < j; ++k) s -= Ml[j * 35 + k] * Ml[j * 35 + k] * Dv[k];
                Dv[j] = s;
            }
            __syncthreads();
            if (t > j && t < 34) {
                float s = Ml[t * 35 + j];
                for (int k = 0; k < j; ++k) s -= Ml[t * 35 + k] * Ml[j * 35 + k] * Dv[k];
                Ml[t * 35 + j] = s / Dv[j];
            }
            __syncthreads();
        }
        if (t < 34) {
            for (int i = 0; i < 34; ++i) {
                float s = (i == t) ? 1.f : 0.f;
                for (int k = 0; k < i; ++k) s -= Ml[i * 35 + k] * Z[k * 35 + t];
                Z[i * 35 + t] = s;
            }
            for (int i = 33; i >= 0; --i) {
                float s = Z[i * 35 + t] / Dv[i];
                for (int k = i + 1; k < 34; ++k) s -= Ml[k * 35 + i] * Z[k * 35 + t];
                Z[i * 35 + t] = s;
            }
        }
        __syncthreads();
        for (int e = t; e < 34 * 34; e += 256) {
            int i = e / 34, j = e - i * 34;
            Minv[c * 1224 + i * 36 + j] = Z[i * 35 + j];
        }
        if (t == 0) {
            float ld = 0.f;
            for (int j = 0; j < 34; ++j) ld += logf(fabsf(Dv[j]));
            float scale = cons[CO_SCALE + c], kN = cons[CO_KN + c], kap = cons[CO_KAPPA];
            float logdet = (float)Dk * logf(scale) + extraf[0] + logf(kN) + logf(kap) + ld;
            cons[CO_BIASF + c] = cons[CO_BIASA + c] - 0.5f * logdet;
        }
    }
    grid.sync();

    // ---------------- P6: epilogue, 512 tasks (qt, c) ----------------
    for (int tau = b; tau < 512; tau += 256) {
        int qt = tau >> 5, c = tau & 31;
        float* Mi = smA;          // stride 35
        float* wL = smB;          // stride 68
        float* gsm = sX;          // 34
        float* red = sX + 128;    // 256
        for (int e = t; e < 34 * 34; e += 256) {
            int i = e / 34, j = e - i * 34;
            Mi[i * 35 + j] = Minv[c * 1224 + i * 36 + j];
        }
        if (t < 34)
            gsm[t] = (t < 32) ? Mbuf[c * 1224 + t * 36 + 32]
                              : ((t == 32) ? gmm[c] : Mbuf[c * 1224 + 33 * 36 + 32]);
        __syncthreads();
        for (int e = t; e < 34 * NB; e += 256) {
            int i = e >> 6, qq = e & 63;
            int prow = (i < 32) ? (c * 32 + i) : ((i == 32) ? (Nk + c) : (Nk + Ck));
            wL[i * 68 + qq] = P[(size_t)prow * Qk + qt * NB + qq] - gsm[i];
        }
        __syncthreads();
        {
            int q = t & 63, part = t >> 6;
            int start = (part < 2) ? part * 9 : 18 + (part - 2) * 8;
            int cnt = (part < 2) ? 9 : 8;
            float partial = 0.f;
            for (int i = start; i < start + cnt; ++i) {
                float v = 0.f;
                for (int j = 0; j < 34; ++j) v += Mi[i * 35 + j] * wL[j * 68 + q];
                partial += v * wL[i * 68 + q];
            }
            red[part * 64 + q] = partial;
        }
        __syncthreads();
        if (t < 64) {
            int q = t;
            float quad = red[q] + red[64 + q] + red[128 + q] + red[192 + q];
            int qg = qt * NB + q;
            float w32 = wL[32 * 68 + q];
            float ydist2 = qny[qg] - 2.f * w32 - gmm[c];
            float dd = qno[qg] + mun2o[c] - 2.f * QM[(size_t)c * Qk + qg];
            float scale = cons[CO_SCALE + c], common = cons[CO_COMMON + c];
            float dist = (1.f - REGP) / scale * (ydist2 - quad) + REGP * dd;
            out[(size_t)qg * Ck + c] = cons[CO_BIASF + c] - cons[CO_COEF + c] * log1pf(dist / common);
        }
        __syncthreads();
    }
}

extern "C" void kernel_launch(void* const* d_in, const int* in_sizes, int n_in,
                              void* d_out, int out_size, void* d_ws, size_t ws_size,
                              hipStream_t stream) {
    const float* sx = (const float*)d_in[0];
    const float* qx = (const float*)d_in[1];
    const int* labels = (const int*)d_in[2];
    const float* mvec = (const float*)d_in[3];
    const float* kappa = (const float*)d_in[4];
    const float* nu = (const float*)d_in[5];
    const float* td = (const float*)d_in[6];
    const float* tl = (const float*)d_in[7];
    float* W = (float*)d_ws;
    float* out = (float*)d_out;

    void* args[] = {&sx, &qx, &labels, &mvec, &kappa, &nu, &td, &tl, &W, &out};
    hipLaunchCooperativeKernel((const void*)k_all, dim3(256), dim3(256), args, 0, stream);
}

// Round 5
// 1653.814 us; speedup vs baseline: 3.5078x; 1.1689x over previous
//
#include <hip/hip_runtime.h>
#include <hip/hip_cooperative_groups.h>
#include <math.h>

namespace cg = cooperative_groups;

#define Dk 1024
#define Ck 32
#define Nk 1024
#define Qk 1024
#define REGP 0.5f
#define NB 64
#define NT (Dk/NB)
#define NROWSV (Qk + Nk + Ck + 1)   // 2081 rows: queries, sorted support, mus, m

// consts layout (floats)
#define CO_KAPPA 0
#define CO_NU    1
#define CO_NJ    2
#define CO_KN    34
#define CO_SCALE 66
#define CO_COMMON 98
#define CO_COEF  130
#define CO_BIASA 162
#define CO_BIASF 200
#define CO_TOTAL 256

// workspace offsets (floats)
#define O_Y    ((size_t)0)
#define O_YO   (O_Y + 2112u*1024u)
#define O_W    (O_YO + 2112u*1024u)
#define O_T    (O_W + 1024u*1024u)
#define O_P    (O_T + 512u*512u)
#define O_MU   (O_P + 1088u*1024u)
#define O_QM   (O_MU + 32u*1024u)
#define O_MB   (O_QM + 32u*1024u)
#define O_MI   (O_MB + 32u*1224u)
#define O_QNY  (O_MI + 32u*1224u)
#define O_QNO  (O_QNY + 1024u)
#define O_MUN  (O_QNO + 1024u)
#define O_GMM  (O_MUN + 32u)
#define O_EX   (O_GMM + 32u)
#define O_CONS (O_EX + 16u)
#define O_CIDX (O_CONS + 256u)

__device__ __forceinline__ float wave_red(float s) {
#pragma unroll
    for (int o = 32; o > 0; o >>= 1) s += __shfl_down(s, o, 64);
    return s;
}

// transposed tile load: dst[k*68 + r] = src[(rowbase+r)*ld + colbase + k]
__device__ __forceinline__ void ld_tileT(float* dst, const float* src, int ld,
                                         int rowbase, int rowmax, int colbase, int t) {
    for (int idx = t; idx < NB * NB; idx += 256) {
        int r = idx >> 6, k = idx & 63;
        int gr = rowbase + r;
        dst[k * 68 + r] = (gr < rowmax) ? src[(size_t)gr * ld + colbase + k] : 0.f;
    }
}

// straight tile load: dst[k*68 + c] = src[(rowbase+k)*ld + colbase + c]
__device__ __forceinline__ void ld_tileN(float* dst, const float* src, int ld,
                                         int rowbase, int colbase, int t) {
    for (int idx = t; idx < NB * NB; idx += 256) {
        int k = idx >> 6, c = idx & 63;
        dst[k * 68 + c] = src[(size_t)(rowbase + k) * ld + colbase + c];
    }
}

// acc[r][s] += sum_k At[k][ty*4+r] * Bt[k][tx*4+s]
__device__ __forceinline__ void gemm16(const float* At, const float* Bt,
                                       float acc[4][4], int tx, int ty) {
#pragma unroll 4
    for (int kk = 0; kk < NB; ++kk) {
        float4 a = *(const float4*)(At + kk * 68 + ty * 4);
        float4 b = *(const float4*)(Bt + kk * 68 + tx * 4);
        float av[4] = {a.x, a.y, a.z, a.w};
        float bv[4] = {b.x, b.y, b.z, b.w};
#pragma unroll
        for (int r = 0; r < 4; ++r)
#pragma unroll
            for (int s = 0; s < 4; ++s) acc[r][s] += av[r] * bv[s];
    }
}

__global__ __launch_bounds__(256) void k_all(const float* sx, const float* qx,
                                             const int* labels, const float* mvec,
                                             const float* kappa, const float* nu,
                                             const float* td, const float* tl,
                                             float* Wbuf, float* out) {
    cg::grid_group grid = cg::this_grid();
    __shared__ __align__(16) float smem[9216];
    float* smA = smem;            // 4352
    float* smB = smem + 4352;     // 4352
    float* sX  = smem + 8704;     // 512

    float* Y     = Wbuf + O_Y;
    float* Yo    = Wbuf + O_YO;
    float* W     = Wbuf + O_W;
    float* Tb    = Wbuf + O_T;
    float* P     = Wbuf + O_P;
    float* mu    = Wbuf + O_MU;
    float* QM    = Wbuf + O_QM;
    float* Mbuf  = Wbuf + O_MB;
    float* Minv  = Wbuf + O_MI;
    float* qny   = Wbuf + O_QNY;
    float* qno   = Wbuf + O_QNO;
    float* mun2o = Wbuf + O_MUN;
    float* gmm   = Wbuf + O_GMM;
    float* extraf= Wbuf + O_EX;
    float* cons  = Wbuf + O_CONS;
    int*   cidx  = (int*)(Wbuf + O_CIDX);

    const int b = blockIdx.x, G = gridDim.x;
    const int t = threadIdx.x;
    const int tx = t & 15, ty = t >> 4;
    const int lane = t & 63, wv = t >> 6;

    // ================= P0: stats, logdet, diag-inv, zero-W, qno, copies =================
    for (int tau = b; tau < 387; tau += G) {
        if (tau == 0) {
            int* scnt = (int*)sX;
            if (t < Ck) scnt[t] = 0;
            __syncthreads();
            for (int n = t; n < Nk; n += 256) {
                int l = labels[n];
                int pos = atomicAdd(&scnt[l], 1);
                cidx[l * Nk + pos] = n;
            }
            __syncthreads();
            if (t < Ck) {
                float kap = fabsf(kappa[0]) + 1e-6f;
                float nu_ = fmaxf(nu[0], (float)(Dk - 1) + 1e-6f);
                float Njf = (float)scnt[t];
                float kN = kap + Njf;
                if (t == 0) { cons[CO_KAPPA] = kap; cons[CO_NU] = nu_; }
                cons[CO_NJ + t] = Njf;
                cons[CO_KN + t] = kN;
                cons[CO_SCALE + t] = (kN + 1.0f) / ((nu_ + Njf - (float)Dk + 1.0f) * kN);
                float common = nu_ + Njf + 1.0f - (float)Dk;
                cons[CO_COMMON + t] = common;
                cons[CO_COEF + t] = 0.5f * (common + (float)Dk);
                cons[CO_BIASA + t] = lgammaf(0.5f * (common + (float)Dk)) - lgammaf(0.5f * common)
                                     - 0.5f * (float)Dk * logf(common);
            }
            __syncthreads();
        } else if (tau == 1) {
            float s = 0.f;
            for (int i = t; i < Dk; i += 256) s += logf(fabsf(td[i]));
            s = wave_red(s);
            if (lane == 0) sX[wv] = s;
            __syncthreads();
            if (t == 0) extraf[0] = 2.f * (sX[0] + sX[1] + sX[2] + sX[3]);
            __syncthreads();
        } else if (tau < 18) {
            int I = tau - 2, b0 = I * NB;
            for (int idx = t; idx < NB * NB; idx += 256) {
                int r = idx >> 6, c = idx & 63;
                float v;
                if (c < r) v = tl[(size_t)(b0 + r) * Dk + b0 + c];
                else if (c == r) v = fabsf(td[b0 + r]);
                else v = 0.f;
                smA[r * 68 + c] = v;
            }
            __syncthreads();
            if (t < NB) {
                int j = t;
                smB[j * 68 + j] = 1.f / smA[j * 68 + j];
                for (int i = j + 1; i < NB; ++i) {
                    float s = 0.f;
                    for (int k = j; k < i; ++k) s += smA[i * 68 + k] * smB[k * 68 + j];
                    smB[i * 68 + j] = -s / smA[i * 68 + i];
                }
            }
            __syncthreads();
            for (int idx = t; idx < NB * NB; idx += 256) {
                int r = idx >> 6, c = idx & 63;
                W[(size_t)(b0 + r) * Dk + b0 + c] = (c <= r) ? smB[r * 68 + c] : 0.f;
            }
            __syncthreads();
        } else if (tau < 258) {
            int e = tau - 18;
            int i = e / 15, jr = e % 15;
            int j = jr + (jr >= i ? 1 : 0);
            for (int idx = t; idx < NB * 16; idx += 256) {
                int r = idx >> 4, c4 = idx & 15;
                ((float4*)(W + (size_t)(i * NB + r) * Dk + j * NB))[c4] = make_float4(0, 0, 0, 0);
            }
        } else if (tau < 322) {
            int rbase = (tau - 258) * 16;
            for (int j = wv; j < 16; j += 4) {
                const float* row = qx + (size_t)(rbase + j) * Dk;
                float s = 0.f;
                for (int d = lane; d < Dk; d += 64) { float v = row[d]; s += v * v; }
                s = wave_red(s);
                if (lane == 0) qno[rbase + j] = s;
            }
        } else if (tau < 386) {
            int rbase = (tau - 322) * 16;
            for (int j = 0; j < 16; ++j) {
                int r = rbase + j;
                ((float4*)(Y + (size_t)r * Dk))[t] = ((const float4*)(qx + (size_t)r * Dk))[t];
            }
        } else {
            ((float4*)(Y + (size_t)(Qk + Nk + Ck) * Dk))[t] = ((const float4*)mvec)[t];
        }
    }
    grid.sync();

    // ================= P1: mu, sorted-support copy =================
    for (int tau = b; tau < 192; tau += G) {
        if (tau < 128) {
            int c = tau >> 2;
            int d = ((tau & 3) << 8) + t;
            int Nj = (int)cons[CO_NJ + c];
            float kap = cons[CO_KAPPA], kN = cons[CO_KN + c];
            float acc = 0.f;
            for (int s = 0; s < Nj; ++s) acc += sx[(size_t)cidx[c * Nk + s] * Dk + d];
            mu[c * Dk + d] = (kap * mvec[d] + acc) / kN;
        } else {
            int rbase = (tau - 128) * 16;
            for (int j = 0; j < 16; ++j) {
                int n = rbase + j;
                int srcrow = cidx[(n >> 5) * Nk + (n & 31)];
                ((float4*)(Y + (size_t)(Qk + n) * Dk))[t] = ((const float4*)(sx + (size_t)srcrow * Dk))[t];
            }
        }
    }
    grid.sync();

    // ================= P2: mu rows -> Y, mu norms =================
    for (int tau = b; tau < 64; tau += G) {
        if (tau < 32) {
            int c = tau;
            ((float4*)(Y + (size_t)(Qk + Nk + c) * Dk))[t] = ((const float4*)(mu + (size_t)c * Dk))[t];
        } else {
            int c = tau - 32;
            if (wv == 0) {
                float s = 0.f;
                for (int d = lane; d < Dk; d += 64) { float v = mu[c * Dk + d]; s += v * v; }
                s = wave_red(s);
                if (lane == 0) mun2o[c] = s;
            }
        }
    }
    grid.sync();

    // ================= trtri by recursive doubling: W = Lhat^-1 =================
    for (int l = 1; l <= 4; ++l) {
        int h = 32 << l;          // half-size being merged
        int ht = h >> 6;          // tiles per dim
        int pairs = 16 >> l;
        int ntask = pairs * ht * ht;
        // phase A: T = B * Ainv
        for (int tau = b; tau < ntask; tau += G) {
            int p = tau / (ht * ht), rr = tau % (ht * ht);
            int i = rr / ht, j = rr % ht;
            int pb = p * 2 * h;
            float acc[4][4] = {};
            for (int k = 0; k < ht; ++k) {
                ld_tileT(smA, tl, Dk, pb + h + i * NB, Dk, pb + k * NB, t);
                ld_tileN(smB, W, Dk, pb + k * NB, pb + j * NB, t);
                __syncthreads();
                gemm16(smA, smB, acc, tx, ty);
                __syncthreads();
            }
            float* Tp = Tb + (size_t)p * h * h;
#pragma unroll
            for (int r = 0; r < 4; ++r)
#pragma unroll
                for (int s = 0; s < 4; ++s)
                    Tp[(size_t)(i * NB + ty * 4 + r) * h + j * NB + tx * 4 + s] = acc[r][s];
        }
        grid.sync();
        // phase B: W_off = -Cinv * T
        for (int tau = b; tau < ntask; tau += G) {
            int p = tau / (ht * ht), rr = tau % (ht * ht);
            int i = rr / ht, j = rr % ht;
            int pb = p * 2 * h;
            const float* Tp = Tb + (size_t)p * h * h;
            float acc[4][4] = {};
            for (int k = 0; k < ht; ++k) {
                ld_tileT(smA, W, Dk, pb + h + i * NB, Dk, pb + h + k * NB, t);
                ld_tileN(smB, Tp, h, k * NB, j * NB, t);
                __syncthreads();
                gemm16(smA, smB, acc, tx, ty);
                __syncthreads();
            }
#pragma unroll
            for (int r = 0; r < 4; ++r)
#pragma unroll
                for (int s = 0; s < 4; ++s)
                    W[(size_t)(pb + h + i * NB + ty * 4 + r) * Dk + pb + j * NB + tx * 4 + s] = -acc[r][s];
        }
        grid.sync();
    }

    // ================= Ygemm: Yo = Y * W^T  (tile jt needs kt <= jt) =================
    for (int tau = b; tau < 33 * 16; tau += G) {
        int rt = tau >> 4, jt = tau & 15;
        float acc[4][4] = {};
        for (int kt = 0; kt <= jt; ++kt) {
            ld_tileT(smA, Y, Dk, rt * NB, NROWSV, kt * NB, t);
            ld_tileT(smB, W, Dk, jt * NB, Dk, kt * NB, t);
            __syncthreads();
            gemm16(smA, smB, acc, tx, ty);
            __syncthreads();
        }
#pragma unroll
        for (int r = 0; r < 4; ++r) {
            int gr = rt * NB + ty * 4 + r;
            if (gr < NROWSV)
#pragma unroll
                for (int s = 0; s < 4; ++s)
                    Yo[(size_t)gr * Dk + jt * NB + tx * 4 + s] = acc[r][s];
        }
    }
    grid.sync();

    // ================= P4: P gemm (272), QM (16), gram (32), qny (64) =================
    for (int tau = b; tau < 384; tau += G) {
        if (tau < 272) {
            int qt = tau & 15, nt = tau >> 4;
            float acc[4][4] = {};
            for (int kt = 0; kt < NT; ++kt) {
                ld_tileT(smA, Yo + (size_t)Qk * Dk, Dk, nt * NB, Nk + Ck + 1, kt * NB, t);
                ld_tileT(smB, Yo, Dk, qt * NB, Qk, kt * NB, t);
                __syncthreads();
                gemm16(smA, smB, acc, tx, ty);
                __syncthreads();
            }
#pragma unroll
            for (int r = 0; r < 4; ++r) {
                int n = nt * NB + ty * 4 + r;
                if (n < Nk + Ck + 1)
#pragma unroll
                    for (int s = 0; s < 4; ++s)
                        P[(size_t)n * Qk + qt * NB + tx * 4 + s] = acc[r][s];
            }
        } else if (tau < 288) {
            int qt = tau - 272;
            float acc[4][4] = {};
            for (int kt = 0; kt < NT; ++kt) {
                ld_tileT(smA, mu, Dk, 0, Ck, kt * NB, t);
                ld_tileT(smB, qx, Dk, qt * NB, Qk, kt * NB, t);
                __syncthreads();
                gemm16(smA, smB, acc, tx, ty);
                __syncthreads();
            }
#pragma unroll
            for (int r = 0; r < 4; ++r) {
                int c = ty * 4 + r;
                if (c < Ck)
#pragma unroll
                    for (int s = 0; s < 4; ++s)
                        QM[(size_t)c * Qk + qt * NB + tx * 4 + s] = acc[r][s];
            }
        } else if (tau < 320) {
            int c = tau - 288;
            float accg[5];
            int iu[5], ju[5];
#pragma unroll
            for (int u = 0; u < 5; ++u) {
                int e = t + u * 256;
                iu[u] = e / 34; ju[u] = e - iu[u] * 34;
                accg[u] = 0.f;
            }
            for (int kt = 0; kt < NT; ++kt) {
                for (int e2 = t; e2 < 34 * NB; e2 += 256) {
                    int i = e2 >> 6, k = e2 & 63;
                    int yr = (i < 32) ? (Qk + c * 32 + i) : ((i == 32) ? (Qk + Nk + c) : (Qk + Nk + Ck));
                    smA[i * 68 + k] = Yo[(size_t)yr * Dk + kt * NB + k];
                }
                __syncthreads();
#pragma unroll
                for (int u = 0; u < 5; ++u) {
                    int e = t + u * 256;
                    if (e < 1156) {
                        float s = 0.f;
                        for (int k = 0; k < NB; ++k) s += smA[iu[u] * 68 + k] * smA[ju[u] * 68 + k];
                        accg[u] += s;
                    }
                }
                __syncthreads();
            }
            float kN = cons[CO_KN + c], kap = cons[CO_KAPPA];
#pragma unroll
            for (int u = 0; u < 5; ++u) {
                int e = t + u * 256;
                if (e < 1156) {
                    int i = iu[u], j = ju[u];
                    float v = accg[u];
                    if (i == 32 && j == 32) { gmm[c] = v; v += -1.f / kN; }
                    else if (i == 33 && j == 33) v += 1.f / kap;
                    else if (i == j) v += 1.f;
                    Mbuf[c * 1224 + i * 36 + j] = v;
                }
            }
        } else {
            int rbase = (tau - 320) * 16;
            for (int j = wv; j < 16; j += 4) {
                const float* row = Yo + (size_t)(rbase + j) * Dk;
                float s = 0.f;
                for (int d = lane; d < Dk; d += 64) { float v = row[d]; s += v * v; }
                s = wave_red(s);
                if (lane == 0) qny[rbase + j] = s;
            }
        }
    }
    grid.sync();

    // ================= P5: 34x34 LDL + inverse + bias per class =================
    for (int tau = b; tau < Ck; tau += G) {
        int c = tau;
        float* Ml = smA;   // stride 35
        float* Z  = smB;   // stride 35
        float* Dv = sX;
        for (int e = t; e < 34 * 34; e += 256) {
            int i = e / 34, j = e - i * 34;
            Ml[i * 35 + j] = Mbuf[c * 1224 + i * 36 + j];
        }
        __syncthreads();
        for (int j = 0; j < 34; ++j) {
            if (t == 0) {
                float s = Ml[j * 35 + j];
                for (int k = 0; k < j; ++k) s -= Ml[j * 35 + k] * Ml[j * 35 + k] * Dv[k];
                Dv[j] = s;
            }
            __syncthreads();
            if (t > j && t < 34) {
                float s = Ml[t * 35 + j];
                for (int k = 0; k < j; ++k) s -= Ml[t * 35 + k] * Ml[j * 35 + k] * Dv[k];
                Ml[t * 35 + j] = s / Dv[j];
            }
            __syncthreads();
        }
        if (t < 34) {
            for (int i = 0; i < 34; ++i) {
                float s = (i == t) ? 1.f : 0.f;
                for (int k = 0; k < i; ++k) s -= Ml[i * 35 + k] * Z[k * 35 + t];
                Z[i * 35 + t] = s;
            }
            for (int i = 33; i >= 0; --i) {
                float s = Z[i * 35 + t] / Dv[i];
                for (int k = i + 1; k < 34; ++k) s -= Ml[k * 35 + i] * Z[k * 35 + t];
                Z[i * 35 + t] = s;
            }
        }
        __syncthreads();
        for (int e = t; e < 34 * 34; e += 256) {
            int i = e / 34, j = e - i * 34;
            Minv[c * 1224 + i * 36 + j] = Z[i * 35 + j];
        }
        if (t == 0) {
            float ld = 0.f;
            for (int j = 0; j < 34; ++j) ld += logf(fabsf(Dv[j]));
            float scale = cons[CO_SCALE + c], kN = cons[CO_KN + c], kap = cons[CO_KAPPA];
            float logdet = (float)Dk * logf(scale) + extraf[0] + logf(kN) + logf(kap) + ld;
            cons[CO_BIASF + c] = cons[CO_BIASA + c] - 0.5f * logdet;
        }
        __syncthreads();
    }
    grid.sync();

    // ================= P6: epilogue, 512 tasks (qt, c) =================
    for (int tau = b; tau < 512; tau += G) {
        int qt = tau >> 5, c = tau & 31;
        float* Mi = smA;          // stride 35
        float* wL = smB;          // stride 68
        float* gsm = sX;          // 34
        float* red = sX + 128;    // 256
        for (int e = t; e < 34 * 34; e += 256) {
            int i = e / 34, j = e - i * 34;
            Mi[i * 35 + j] = Minv[c * 1224 + i * 36 + j];
        }
        if (t < 34)
            gsm[t] = (t < 32) ? Mbuf[c * 1224 + t * 36 + 32]
                              : ((t == 32) ? gmm[c] : Mbuf[c * 1224 + 33 * 36 + 32]);
        __syncthreads();
        for (int e = t; e < 34 * NB; e += 256) {
            int i = e >> 6, qq = e & 63;
            int prow = (i < 32) ? (c * 32 + i) : ((i == 32) ? (Nk + c) : (Nk + Ck));
            wL[i * 68 + qq] = P[(size_t)prow * Qk + qt * NB + qq] - gsm[i];
        }
        __syncthreads();
        {
            int q = t & 63, part = t >> 6;
            int start = (part < 2) ? part * 9 : 18 + (part - 2) * 8;
            int cnt = (part < 2) ? 9 : 8;
            float partial = 0.f;
            for (int i = start; i < start + cnt; ++i) {
                float v = 0.f;
                for (int j = 0; j < 34; ++j) v += Mi[i * 35 + j] * wL[j * 68 + q];
                partial += v * wL[i * 68 + q];
            }
            red[part * 64 + q] = partial;
        }
        __syncthreads();
        if (t < 64) {
            int q = t;
            float quad = red[q] + red[64 + q] + red[128 + q] + red[192 + q];
            int qg = qt * NB + q;
            float w32 = wL[32 * 68 + q];
            float ydist2 = qny[qg] - 2.f * w32 - gmm[c];
            float dd = qno[qg] + mun2o[c] - 2.f * QM[(size_t)c * Qk + qg];
            float scale = cons[CO_SCALE + c], common = cons[CO_COMMON + c];
            float dist = (1.f - REGP) / scale * (ydist2 - quad) + REGP * dd;
            out[(size_t)qg * Ck + c] = cons[CO_BIASF + c] - cons[CO_COEF + c] * log1pf(dist / common);
        }
        __syncthreads();
    }
}

extern "C" void kernel_launch(void* const* d_in, const int* in_sizes, int n_in,
                              void* d_out, int out_size, void* d_ws, size_t ws_size,
                              hipStream_t stream) {
    const float* sx = (const float*)d_in[0];
    const float* qx = (const float*)d_in[1];
    const int* labels = (const int*)d_in[2];
    const float* mvec = (const float*)d_in[3];
    const float* kappa = (const float*)d_in[4];
    const float* nu = (const float*)d_in[5];
    const float* td = (const float*)d_in[6];
    const float* tl = (const float*)d_in[7];
    float* W = (float*)d_ws;
    float* out = (float*)d_out;

    int nb = 1;
    hipOccupancyMaxActiveBlocksPerMultiprocessor(&nb, (const void*)k_all, 256, 0);
    if (nb < 1) nb = 1;
    if (nb > 4) nb = 4;
    int grid = nb * 256;

    void* args[] = {&sx, &qx, &labels, &mvec, &kappa, &nu, &td, &tl, &W, &out};
    hipLaunchCooperativeKernel((const void*)k_all, dim3(grid), dim3(256), args, 0, stream);
}

// Round 6
// 917.828 us; speedup vs baseline: 6.3206x; 1.8019x over previous
//
#include <hip/hip_runtime.h>
#include <hip/hip_cooperative_groups.h>
#include <math.h>

namespace cg = cooperative_groups;

#define Dk 1024
#define Ck 32
#define Nk 1024
#define Qk 1024
#define REGP 0.5f
#define NB 64
#define NT (Dk/NB)
#define NROWSV (Qk + Nk + Ck + 1)   // 2081 rows: queries, sorted support, mus, m

// consts layout (floats)
#define CO_KAPPA 0
#define CO_NU    1
#define CO_NJ    2
#define CO_KN    34
#define CO_SCALE 66
#define CO_COMMON 98
#define CO_COEF  130
#define CO_BIASA 162
#define CO_BIASF 200
#define CO_TOTAL 256

// workspace offsets (floats)
#define O_Y    ((size_t)0)
#define O_YO   (O_Y + 2112u*1024u)
#define O_W    (O_YO + 2112u*1024u)
#define O_T    (O_W + 1024u*1024u)
#define O_P    (O_T + 512u*512u)
#define O_MU   (O_P + 1088u*1024u)
#define O_QM   (O_MU + 32u*1024u)
#define O_MB   (O_QM + 32u*1024u)
#define O_MI   (O_MB + 32u*1224u)
#define O_QNY  (O_MI + 32u*1224u)
#define O_QNO  (O_QNY + 1024u)
#define O_MUN  (O_QNO + 1024u)
#define O_GMM  (O_MUN + 32u)
#define O_EX   (O_GMM + 32u)
#define O_CONS (O_EX + 16u)
#define O_CIDX (O_CONS + 256u)

__device__ __forceinline__ float wave_red(float s) {
#pragma unroll
    for (int o = 32; o > 0; o >>= 1) s += __shfl_down(s, o, 64);
    return s;
}

// fetch a 64x64 tile as 4 float4 per thread (independent, batched loads)
__device__ __forceinline__ void fetch4(float4* reg, const float* src, int ld,
                                       int rowbase, int rowmax, int colbase, int t) {
#pragma unroll
    for (int u = 0; u < 4; ++u) {
        int slot = t + u * 256;           // 0..1023
        int r = slot >> 4, c4 = slot & 15;
        int gr = rowbase + r;
        reg[u] = (gr < rowmax) ? *(const float4*)(src + (size_t)gr * ld + colbase + c4 * 4)
                               : make_float4(0.f, 0.f, 0.f, 0.f);
    }
}
// store transposed: dst[k*68 + r] = tile[r][k]
__device__ __forceinline__ void stT(float* dst, const float4* reg, int t) {
#pragma unroll
    for (int u = 0; u < 4; ++u) {
        int slot = t + u * 256;
        int r = slot >> 4, c4 = slot & 15;
        dst[(c4 * 4 + 0) * 68 + r] = reg[u].x;
        dst[(c4 * 4 + 1) * 68 + r] = reg[u].y;
        dst[(c4 * 4 + 2) * 68 + r] = reg[u].z;
        dst[(c4 * 4 + 3) * 68 + r] = reg[u].w;
    }
}
// store straight: dst[r*68 + c] = tile[r][c]  (float4 LDS writes)
__device__ __forceinline__ void stN(float* dst, const float4* reg, int t) {
#pragma unroll
    for (int u = 0; u < 4; ++u) {
        int slot = t + u * 256;
        int r = slot >> 4, c4 = slot & 15;
        *(float4*)(dst + r * 68 + c4 * 4) = reg[u];
    }
}

// acc[r][s] += sum_k At[k][ty*4+r] * Bt[k][tx*4+s]
__device__ __forceinline__ void gemm16(const float* At, const float* Bt,
                                       float acc[4][4], int tx, int ty) {
#pragma unroll 4
    for (int kk = 0; kk < NB; ++kk) {
        float4 a = *(const float4*)(At + kk * 68 + ty * 4);
        float4 b = *(const float4*)(Bt + kk * 68 + tx * 4);
        float av[4] = {a.x, a.y, a.z, a.w};
        float bv[4] = {b.x, b.y, b.z, b.w};
#pragma unroll
        for (int r = 0; r < 4; ++r)
#pragma unroll
            for (int s = 0; s < 4; ++s) acc[r][s] += av[r] * bv[s];
    }
}

// double-buffered k-loop tile GEMM. Per kt: A cols advance by aColStep, rows by aRowStep (same for B).
__device__ __forceinline__ void mm_task(
    const float* aSrc, int aLd, int aRow, int aRowMax, int aCol, int aRowStep, int aColStep,
    const float* bSrc, int bLd, int bRow, int bRowMax, int bCol, int bRowStep, int bColStep,
    bool bTrans, int k0, int k1,
    float acc[4][4], float* smA, float* smB, int t, int tx, int ty)
{
    float4 ra[4], rb[4];
    fetch4(ra, aSrc, aLd, aRow + k0 * aRowStep, aRowMax, aCol + k0 * aColStep, t);
    fetch4(rb, bSrc, bLd, bRow + k0 * bRowStep, bRowMax, bCol + k0 * bColStep, t);
    stT(smA, ra, t);
    if (bTrans) stT(smB, rb, t); else stN(smB, rb, t);
    __syncthreads();
    for (int kt = k0; kt < k1; ++kt) {
        if (kt + 1 < k1) {
            fetch4(ra, aSrc, aLd, aRow + (kt + 1) * aRowStep, aRowMax, aCol + (kt + 1) * aColStep, t);
            fetch4(rb, bSrc, bLd, bRow + (kt + 1) * bRowStep, bRowMax, bCol + (kt + 1) * bColStep, t);
        }
        gemm16(smA, smB, acc, tx, ty);
        __syncthreads();
        if (kt + 1 < k1) {
            stT(smA, ra, t);
            if (bTrans) stT(smB, rb, t); else stN(smB, rb, t);
        }
        __syncthreads();
    }
}

__global__ __launch_bounds__(256) void k_all(const float* sx, const float* qx,
                                             const int* labels, const float* mvec,
                                             const float* kappa, const float* nu,
                                             const float* td, const float* tl,
                                             float* Wbuf, float* out) {
    cg::grid_group grid = cg::this_grid();
    __shared__ __align__(16) float smem[9216];
    float* smA = smem;            // 4352
    float* smB = smem + 4352;     // 4352
    float* sX  = smem + 8704;     // 512

    float* Y     = Wbuf + O_Y;
    float* Yo    = Wbuf + O_YO;
    float* W     = Wbuf + O_W;
    float* Tb    = Wbuf + O_T;
    float* P     = Wbuf + O_P;
    float* mu    = Wbuf + O_MU;
    float* QM    = Wbuf + O_QM;
    float* Mbuf  = Wbuf + O_MB;
    float* Minv  = Wbuf + O_MI;
    float* qny   = Wbuf + O_QNY;
    float* qno   = Wbuf + O_QNO;
    float* mun2o = Wbuf + O_MUN;
    float* gmm   = Wbuf + O_GMM;
    float* extraf= Wbuf + O_EX;
    float* cons  = Wbuf + O_CONS;
    int*   cidx  = (int*)(Wbuf + O_CIDX);

    const int b = blockIdx.x, G = gridDim.x;
    const int t = threadIdx.x;
    const int tx = t & 15, ty = t >> 4;
    const int lane = t & 63, wv = t >> 6;
    const int BIG = 1 << 30;

    // ========== P0: stats, logdet, diag-inv, zero accum buffers, qno, copies ==========
    for (int tau = b; tau < 353; tau += G) {
        if (tau == 0) {
            int* scnt = (int*)sX;
            if (t < Ck) scnt[t] = 0;
            __syncthreads();
            for (int n = t; n < Nk; n += 256) {
                int l = labels[n];
                int pos = atomicAdd(&scnt[l], 1);
                cidx[l * Nk + pos] = n;
            }
            __syncthreads();
            if (t < Ck) {
                float kap = fabsf(kappa[0]) + 1e-6f;
                float nu_ = fmaxf(nu[0], (float)(Dk - 1) + 1e-6f);
                float Njf = (float)scnt[t];
                float kN = kap + Njf;
                if (t == 0) { cons[CO_KAPPA] = kap; cons[CO_NU] = nu_; }
                cons[CO_NJ + t] = Njf;
                cons[CO_KN + t] = kN;
                cons[CO_SCALE + t] = (kN + 1.0f) / ((nu_ + Njf - (float)Dk + 1.0f) * kN);
                float common = nu_ + Njf + 1.0f - (float)Dk;
                cons[CO_COMMON + t] = common;
                cons[CO_COEF + t] = 0.5f * (common + (float)Dk);
                cons[CO_BIASA + t] = lgammaf(0.5f * (common + (float)Dk)) - lgammaf(0.5f * common)
                                     - 0.5f * (float)Dk * logf(common);
            }
            __syncthreads();
        } else if (tau == 1) {
            float s = 0.f;
            for (int i = t; i < Dk; i += 256) s += logf(fabsf(td[i]));
            s = wave_red(s);
            if (lane == 0) sX[wv] = s;
            __syncthreads();
            if (t == 0) extraf[0] = 2.f * (sX[0] + sX[1] + sX[2] + sX[3]);
            __syncthreads();
        } else if (tau < 18) {
            int I = tau - 2, b0 = I * NB;
            for (int idx = t; idx < NB * NB; idx += 256) {
                int r = idx >> 6, c = idx & 63;
                float v;
                if (c < r) v = tl[(size_t)(b0 + r) * Dk + b0 + c];
                else if (c == r) v = fabsf(td[b0 + r]);
                else v = 0.f;
                smA[r * 68 + c] = v;
            }
            __syncthreads();
            if (t < NB) {
                int j = t;
                smB[j * 68 + j] = 1.f / smA[j * 68 + j];
                for (int i = j + 1; i < NB; ++i) {
                    float s = 0.f;
                    for (int k = j; k < i; ++k) s += smA[i * 68 + k] * smB[k * 68 + j];
                    smB[i * 68 + j] = -s / smA[i * 68 + i];
                }
            }
            __syncthreads();
            for (int idx = t; idx < NB * NB; idx += 256) {
                int r = idx >> 6, c = idx & 63;
                W[(size_t)(b0 + r) * Dk + b0 + c] = (c <= r) ? smB[r * 68 + c] : 0.f;
            }
            __syncthreads();
        } else if (tau < 150) {        // zero Yo (2112 rows, 16/task)
            int rbase = (tau - 18) * 16;
            for (int j = 0; j < 16; ++j)
                ((float4*)(Yo + (size_t)(rbase + j) * Dk))[t] = make_float4(0, 0, 0, 0);
        } else if (tau < 218) {        // zero P (1088 rows, 16/task)
            int rbase = (tau - 150) * 16;
            for (int j = 0; j < 16; ++j)
                ((float4*)(P + (size_t)(rbase + j) * Qk))[t] = make_float4(0, 0, 0, 0);
        } else if (tau < 220) {        // zero QM
            int base = (tau - 218) * 16384;
            ((float4*)(QM + base))[t] = make_float4(0, 0, 0, 0);
            ((float4*)(QM + base + 4096))[t] = make_float4(0, 0, 0, 0);
            ((float4*)(QM + base + 8192))[t] = make_float4(0, 0, 0, 0);
            ((float4*)(QM + base + 12288))[t] = make_float4(0, 0, 0, 0);
        } else if (tau < 223) {        // zero Mbuf (32*1224 = 39168)
            int base = (tau - 220) * 13056;
            for (int i = t; i < 13056 && base + i < 39168; i += 256) Mbuf[base + i] = 0.f;
        } else if (tau == 223) {       // zero qny, mun2o, gmm
            for (int i = t; i < 1024; i += 256) qny[i] = 0.f;
            if (t < 32) { mun2o[t] = 0.f; gmm[t] = 0.f; }
        } else if (tau < 288) {        // qno (16 rows/task)
            int rbase = (tau - 224) * 16;
            for (int j = wv; j < 16; j += 4) {
                const float* row = qx + (size_t)(rbase + j) * Dk;
                float s = 0.f;
                for (int d = lane; d < Dk; d += 64) { float v = row[d]; s += v * v; }
                s = wave_red(s);
                if (lane == 0) qno[rbase + j] = s;
            }
        } else if (tau < 352) {        // copy queries into Y
            int rbase = (tau - 288) * 16;
            for (int j = 0; j < 16; ++j) {
                int r = rbase + j;
                ((float4*)(Y + (size_t)r * Dk))[t] = ((const float4*)(qx + (size_t)r * Dk))[t];
            }
        } else {                       // m row
            ((float4*)(Y + (size_t)(Qk + Nk + Ck) * Dk))[t] = ((const float4*)mvec)[t];
        }
    }
    grid.sync();

    // ========== P1: mu (+Y mu-row +mun2o), sorted-support copy ==========
    for (int tau = b; tau < 192; tau += G) {
        if (tau < 128) {
            int c = tau >> 2;
            int d = ((tau & 3) << 8) + t;
            int Nj = (int)cons[CO_NJ + c];
            float kap = cons[CO_KAPPA], kN = cons[CO_KN + c];
            float acc = 0.f;
            for (int s = 0; s < Nj; ++s) acc += sx[(size_t)cidx[c * Nk + s] * Dk + d];
            float muv = (kap * mvec[d] + acc) / kN;
            mu[c * Dk + d] = muv;
            Y[(size_t)(Qk + Nk + c) * Dk + d] = muv;
            float s2 = wave_red(muv * muv);
            if (lane == 0) sX[wv] = s2;
            __syncthreads();
            if (t == 0) atomicAdd(&mun2o[c], sX[0] + sX[1] + sX[2] + sX[3]);
            __syncthreads();
        } else {
            int rbase = (tau - 128) * 16;
            for (int j = 0; j < 16; ++j) {
                int n = rbase + j;
                int srcrow = cidx[(n >> 5) * Nk + (n & 31)];
                ((float4*)(Y + (size_t)(Qk + n) * Dk))[t] = ((const float4*)(sx + (size_t)srcrow * Dk))[t];
            }
        }
    }
    grid.sync();

    // ========== T1: trtri level-1 (merged A+B, local) + QM split-K ==========
    for (int tau = b; tau < 72; tau += G) {
        if (tau < 8) {
            int pb = tau * 128;
            float acc[4][4] = {};
            // T = B * Ainv : At = tl rows pb+64 (T), Bt = W rows pb (N)
            mm_task(tl, Dk, pb + 64, BIG, pb, 0, NB,
                    W, Dk, pb, BIG, pb, NB, 0, false, 0, 1,
                    acc, smA, smB, t, tx, ty);
            // smB <- T (straight layout), smA <- Cinv transposed
            {
                float4 ra[4];
                fetch4(ra, W, Dk, pb + 64, BIG, pb + 64, t);
#pragma unroll
                for (int r = 0; r < 4; ++r)
#pragma unroll
                    for (int s = 0; s < 4; ++s)
                        smB[(ty * 4 + r) * 68 + tx * 4 + s] = acc[r][s];
                stT(smA, ra, t);
            }
            __syncthreads();
            float acc2[4][4] = {};
            gemm16(smA, smB, acc2, tx, ty);
            __syncthreads();
#pragma unroll
            for (int r = 0; r < 4; ++r)
#pragma unroll
                for (int s = 0; s < 4; ++s)
                    W[(size_t)(pb + 64 + ty * 4 + r) * Dk + pb + tx * 4 + s] = -acc2[r][s];
        } else {
            int e = tau - 8;
            int qt = e >> 2, kc = e & 3;
            float acc[4][4] = {};
            mm_task(mu, Dk, 0, Ck, 0, 0, NB,
                    qx, Dk, qt * NB, Qk, 0, 0, NB, true, kc * 4, kc * 4 + 4,
                    acc, smA, smB, t, tx, ty);
#pragma unroll
            for (int r = 0; r < 4; ++r) {
                int c = ty * 4 + r;
                if (c < Ck)
#pragma unroll
                    for (int s = 0; s < 4; ++s)
                        atomicAdd(&QM[(size_t)c * Qk + qt * NB + tx * 4 + s], acc[r][s]);
            }
        }
    }
    grid.sync();

    // ========== trtri levels 2..4 ==========
    for (int l = 2; l <= 4; ++l) {
        int h = 32 << l;
        int ht = h >> 6;
        int pairs = 16 >> l;
        int ntask = pairs * ht * ht;
        for (int tau = b; tau < ntask; tau += G) {     // phase A: T = B * Ainv
            int p = tau / (ht * ht), rr = tau % (ht * ht);
            int i = rr / ht, j = rr % ht;
            int pb = p * 2 * h;
            float acc[4][4] = {};
            mm_task(tl, Dk, pb + h + i * NB, BIG, pb, 0, NB,
                    W, Dk, pb, BIG, pb + j * NB, NB, 0, false, 0, ht,
                    acc, smA, smB, t, tx, ty);
            float* Tp = Tb + (size_t)p * h * h;
#pragma unroll
            for (int r = 0; r < 4; ++r)
#pragma unroll
                for (int s = 0; s < 4; ++s)
                    Tp[(size_t)(i * NB + ty * 4 + r) * h + j * NB + tx * 4 + s] = acc[r][s];
        }
        grid.sync();
        for (int tau = b; tau < ntask; tau += G) {     // phase B: W_off = -Cinv * T
            int p = tau / (ht * ht), rr = tau % (ht * ht);
            int i = rr / ht, j = rr % ht;
            int pb = p * 2 * h;
            const float* Tp = Tb + (size_t)p * h * h;
            float acc[4][4] = {};
            mm_task(W, Dk, pb + h + i * NB, BIG, pb + h, 0, NB,
                    Tp, h, 0, BIG, j * NB, NB, 0, false, 0, ht,
                    acc, smA, smB, t, tx, ty);
#pragma unroll
            for (int r = 0; r < 4; ++r)
#pragma unroll
                for (int s = 0; s < 4; ++s)
                    W[(size_t)(pb + h + i * NB + ty * 4 + r) * Dk + pb + j * NB + tx * 4 + s] = -acc[r][s];
        }
        grid.sync();
    }

    // ========== Ygemm split-K: Yo += Y * W^T ==========
    for (int e = b; e < 33 * 40; e += G) {
        int rt = e / 40, w = e - rt * 40;
        int jt, kc;
        if (w < 4) { jt = w; kc = 0; }
        else if (w < 12) { jt = 4 + ((w - 4) >> 1); kc = (w - 4) & 1; }
        else if (w < 24) { jt = 8 + (w - 12) / 3; kc = (w - 12) % 3; }
        else { jt = 12 + ((w - 24) >> 2); kc = (w - 24) & 3; }
        int k0 = kc * 4, k1 = min(jt + 1, k0 + 4);
        float acc[4][4] = {};
        mm_task(Y, Dk, rt * NB, NROWSV, 0, 0, NB,
                W, Dk, jt * NB, BIG, 0, 0, NB, true, k0, k1,
                acc, smA, smB, t, tx, ty);
#pragma unroll
        for (int r = 0; r < 4; ++r) {
            int gr = rt * NB + ty * 4 + r;
            if (gr < NROWSV)
#pragma unroll
                for (int s = 0; s < 4; ++s)
                    atomicAdd(&Yo[(size_t)gr * Dk + jt * NB + tx * 4 + s], acc[r][s]);
        }
    }
    grid.sync();

    // ========== P4: P split-K (1088), gram split-K (128), qny (64) ==========
    for (int tau = b; tau < 1280; tau += G) {
        if (tau < 1088) {
            int kc = tau & 3, qt = (tau >> 2) & 15, nt = tau >> 6;
            float acc[4][4] = {};
            mm_task(Yo + (size_t)Qk * Dk, Dk, nt * NB, Nk + Ck + 1, 0, 0, NB,
                    Yo, Dk, qt * NB, Qk, 0, 0, NB, true, kc * 4, kc * 4 + 4,
                    acc, smA, smB, t, tx, ty);
#pragma unroll
            for (int r = 0; r < 4; ++r) {
                int n = nt * NB + ty * 4 + r;
                if (n < Nk + Ck + 1)
#pragma unroll
                    for (int s = 0; s < 4; ++s)
                        atomicAdd(&P[(size_t)n * Qk + qt * NB + tx * 4 + s], acc[r][s]);
            }
        } else if (tau < 1216) {
            int g = tau - 1088;
            int c = g >> 2, kc = g & 3;
            float accg[5];
            int iu[5], ju[5];
#pragma unroll
            for (int u = 0; u < 5; ++u) {
                int e = t + u * 256;
                iu[u] = e / 34; ju[u] = e - iu[u] * 34;
                accg[u] = 0.f;
            }
            for (int kt = kc * 4; kt < kc * 4 + 4; ++kt) {
                for (int e2 = t; e2 < 34 * NB; e2 += 256) {
                    int i = e2 >> 6, k = e2 & 63;
                    int yr = (i < 32) ? (Qk + c * 32 + i) : ((i == 32) ? (Qk + Nk + c) : (Qk + Nk + Ck));
                    smA[i * 68 + k] = Yo[(size_t)yr * Dk + kt * NB + k];
                }
                __syncthreads();
#pragma unroll
                for (int u = 0; u < 5; ++u) {
                    int e = t + u * 256;
                    if (e < 1156) {
                        float s = 0.f;
                        for (int k = 0; k < NB; ++k) s += smA[iu[u] * 68 + k] * smA[ju[u] * 68 + k];
                        accg[u] += s;
                    }
                }
                __syncthreads();
            }
#pragma unroll
            for (int u = 0; u < 5; ++u) {
                int e = t + u * 256;
                if (e < 1156)
                    atomicAdd(&Mbuf[c * 1224 + iu[u] * 36 + ju[u]], accg[u]);
            }
        } else {
            int rbase = (tau - 1216) * 16;
            for (int j = wv; j < 16; j += 4) {
                const float* row = Yo + (size_t)(rbase + j) * Dk;
                float s = 0.f;
                for (int d = lane; d < Dk; d += 64) { float v = row[d]; s += v * v; }
                s = wave_red(s);
                if (lane == 0) qny[rbase + j] = s;
            }
        }
    }
    grid.sync();

    // ========== P5: 34x34 LDL + inverse + bias per class ==========
    for (int tau = b; tau < Ck; tau += G) {
        int c = tau;
        float* Ml = smA;   // stride 35
        float* Z  = smB;   // stride 35
        float* Dv = sX;
        float kN = cons[CO_KN + c], kap = cons[CO_KAPPA];
        for (int e = t; e < 34 * 34; e += 256) {
            int i = e / 34, j = e - i * 34;
            Ml[i * 35 + j] = Mbuf[c * 1224 + i * 36 + j];
        }
        __syncthreads();
        if (t == 0) {
            gmm[c] = Ml[32 * 35 + 32];
            Ml[32 * 35 + 32] += -1.f / kN;
            Ml[33 * 35 + 33] += 1.f / kap;
        }
        if (t < 32) Ml[t * 35 + t] += 1.f;
        __syncthreads();
        for (int j = 0; j < 34; ++j) {
            if (t == 0) {
                float s = Ml[j * 35 + j];
                for (int k = 0; k < j; ++k) s -= Ml[j * 35 + k] * Ml[j * 35 + k] * Dv[k];
                Dv[j] = s;
            }
            __syncthreads();
            if (t > j && t < 34) {
                float s = Ml[t * 35 + j];
                for (int k = 0; k < j; ++k) s -= Ml[t * 35 + k] * Ml[j * 35 + k] * Dv[k];
                Ml[t * 35 + j] = s / Dv[j];
            }
            __syncthreads();
        }
        if (t < 34) {
            for (int i = 0; i < 34; ++i) {
                float s = (i == t) ? 1.f : 0.f;
                for (int k = 0; k < i; ++k) s -= Ml[i * 35 + k] * Z[k * 35 + t];
                Z[i * 35 + t] = s;
            }
            for (int i = 33; i >= 0; --i) {
                float s = Z[i * 35 + t] / Dv[i];
                for (int k = i + 1; k < 34; ++k) s -= Ml[k * 35 + i] * Z[k * 35 + t];
                Z[i * 35 + t] = s;
            }
        }
        __syncthreads();
        for (int e = t; e < 34 * 34; e += 256) {
            int i = e / 34, j = e - i * 34;
            Minv[c * 1224 + i * 36 + j] = Z[i * 35 + j];
        }
        if (t == 0) {
            float ld = 0.f;
            for (int j = 0; j < 34; ++j) ld += logf(fabsf(Dv[j]));
            float scale = cons[CO_SCALE + c];
            float logdet = (float)Dk * logf(scale) + extraf[0] + logf(kN) + logf(kap) + ld;
            cons[CO_BIASF + c] = cons[CO_BIASA + c] - 0.5f * logdet;
        }
        __syncthreads();
    }
    grid.sync();

    // ========== P6: epilogue, 512 tasks (qt, c) ==========
    for (int tau = b; tau < 512; tau += G) {
        int qt = tau >> 5, c = tau & 31;
        float* Mi = smA;          // stride 35
        float* wL = smB;          // stride 68
        float* gsm = sX;          // 34
        float* red = sX + 128;    // 256
        for (int e = t; e < 34 * 34; e += 256) {
            int i = e / 34, j = e - i * 34;
            Mi[i * 35 + j] = Minv[c * 1224 + i * 36 + j];
        }
        if (t < 34)
            gsm[t] = (t < 32) ? Mbuf[c * 1224 + t * 36 + 32]
                              : ((t == 32) ? gmm[c] : Mbuf[c * 1224 + 33 * 36 + 32]);
        __syncthreads();
        for (int e = t; e < 34 * NB; e += 256) {
            int i = e >> 6, qq = e & 63;
            int prow = (i < 32) ? (c * 32 + i) : ((i == 32) ? (Nk + c) : (Nk + Ck));
            wL[i * 68 + qq] = P[(size_t)prow * Qk + qt * NB + qq] - gsm[i];
        }
        __syncthreads();
        {
            int q = t & 63, part = t >> 6;
            int start = (part < 2) ? part * 9 : 18 + (part - 2) * 8;
            int cnt = (part < 2) ? 9 : 8;
            float partial = 0.f;
            for (int i = start; i < start + cnt; ++i) {
                float v = 0.f;
                for (int j = 0; j < 34; ++j) v += Mi[i * 35 + j] * wL[j * 68 + q];
                partial += v * wL[i * 68 + q];
            }
            red[part * 64 + q] = partial;
        }
        __syncthreads();
        if (t < 64) {
            int q = t;
            float quad = red[q] + red[64 + q] + red[128 + q] + red[192 + q];
            int qg = qt * NB + q;
            float w32 = wL[32 * 68 + q];
            float ydist2 = qny[qg] - 2.f * w32 - gmm[c];
            float dd = qno[qg] + mun2o[c] - 2.f * QM[(size_t)c * Qk + qg];
            float scale = cons[CO_SCALE + c], common = cons[CO_COMMON + c];
            float dist = (1.f - REGP) / scale * (ydist2 - quad) + REGP * dd;
            out[(size_t)qg * Ck + c] = cons[CO_BIASF + c] - cons[CO_COEF + c] * log1pf(dist / common);
        }
        __syncthreads();
    }
}

extern "C" void kernel_launch(void* const* d_in, const int* in_sizes, int n_in,
                              void* d_out, int out_size, void* d_ws, size_t ws_size,
                              hipStream_t stream) {
    const float* sx = (const float*)d_in[0];
    const float* qx = (const float*)d_in[1];
    const int* labels = (const int*)d_in[2];
    const float* mvec = (const float*)d_in[3];
    const float* kappa = (const float*)d_in[4];
    const float* nu = (const float*)d_in[5];
    const float* td = (const float*)d_in[6];
    const float* tl = (const float*)d_in[7];
    float* W = (float*)d_ws;
    float* out = (float*)d_out;

    int nb = 1;
    hipOccupancyMaxActiveBlocksPerMultiprocessor(&nb, (const void*)k_all, 256, 0);
    if (nb < 1) nb = 1;
    if (nb > 4) nb = 4;
    int grid = nb * 256;

    void* args[] = {&sx, &qx, &labels, &mvec, &kappa, &nu, &td, &tl, &W, &out};
    hipLaunchCooperativeKernel((const void*)k_all, dim3(grid), dim3(256), args, 0, stream);
}